// Round 10
// baseline (682.368 us; speedup 1.0000x reference)
//
#include <hip/hip_runtime.h>
#include <math.h>

#define BB 4
#define TT 4096
#define NEMB 1024
#define NH 16
#define NKV 8
#define DD 64
#define NCH 64
#define BTOT (BB*TT)
#define KOFF 1024
#define VOFF 1536
#define GK 1024
#define ST2 80   // bf16 LDS row stride: 160B; balanced bank map

typedef __attribute__((ext_vector_type(8))) __bf16 bf16x8;
typedef __attribute__((ext_vector_type(4))) float f32x4;
typedef unsigned short u16;

__device__ inline u16 f2bf(float f){
  union { float f; unsigned u; } x; x.f = f;
  unsigned r = x.u + 0x7fffu + ((x.u >> 16) & 1u);
  return (u16)(r >> 16);
}
__device__ inline float bf2f(u16 u){
  union { unsigned u; float f; } x; x.u = ((unsigned)u) << 16; return x.f;
}
__device__ inline float asf(unsigned u){
  union { unsigned u; float f; } x; x.u = u; return x.f;
}
// HW RTNE pack: low16 = bf16(a), high16 = bf16(b)
__device__ inline unsigned cvtpk(float a, float b){
  unsigned r;
  asm("v_cvt_pk_bf16_f32 %0, %1, %2" : "=v"(r) : "v"(a), "v"(b));
  return r;
}
__device__ inline bf16x8 ldfrag(const u16* a, int outer, int k0, int lm, int lh){
  return *(const bf16x8*)(a + (size_t)(outer + lm)*ST2 + k0 + 8*lh);
}
// Barrier draining only LDS (lgkmcnt), not global traffic.
__device__ inline void lds_barrier(){
  __builtin_amdgcn_sched_barrier(0);
  asm volatile("s_waitcnt lgkmcnt(0)" ::: "memory");
  __builtin_amdgcn_s_barrier();
  __builtin_amdgcn_sched_barrier(0);
}

// ---------------------------------------------------------------------------
// Weight transpose + hi/lo bf16 split (unchanged, proven R5)
// ---------------------------------------------------------------------------
__global__ void __launch_bounds__(256)
wt_split(const float* __restrict__ src, u16* __restrict__ dsth,
         u16* __restrict__ dstl, int N)
{
  __shared__ float ts[64][68];
  const int tid = threadIdx.x;
  const int n0 = blockIdx.x*64, k0 = blockIdx.y*64;
  const int tx = tid & 15, ty = tid >> 4;
#pragma unroll
  for (int i = 0; i < 4; ++i) {
    int k = ty + i*16;
    float4 v = *(const float4*)(src + (size_t)(k0+k)*N + n0 + tx*4);
    ts[k][tx*4+0]=v.x; ts[k][tx*4+1]=v.y; ts[k][tx*4+2]=v.z; ts[k][tx*4+3]=v.w;
  }
  __syncthreads();
#pragma unroll
  for (int i = 0; i < 4; ++i) {
    int n = ty + i*16;
    ushort4 uh, ul;
    float f0 = ts[tx*4+0][n], f1 = ts[tx*4+1][n];
    float f2 = ts[tx*4+2][n], f3 = ts[tx*4+3][n];
    uh.x = f2bf(f0); ul.x = f2bf(f0 - bf2f(uh.x));
    uh.y = f2bf(f1); ul.y = f2bf(f1 - bf2f(uh.y));
    uh.z = f2bf(f2); ul.z = f2bf(f2 - bf2f(uh.z));
    uh.w = f2bf(f3); ul.w = f2bf(f3 - bf2f(uh.w));
    *(ushort4*)(dsth + (size_t)(n0+n)*GK + k0 + tx*4) = uh;
    *(ushort4*)(dstl + (size_t)(n0+n)*GK + k0 + tx*4) = ul;
  }
}

// ---------------------------------------------------------------------------
// QKV GEMM (unchanged from R8/R9)
// ---------------------------------------------------------------------------
__global__ void __launch_bounds__(256)
gemm_qkv(const float* __restrict__ x,
         const u16* __restrict__ Bth, const u16* __restrict__ Btl,
         u16* __restrict__ qb, u16* __restrict__ kb, float* __restrict__ vb,
         const float* __restrict__ cosb, const float* __restrict__ sinb)
{
  __shared__ u16 AsH[128*64];
  __shared__ u16 AsL[128*64];
  __shared__ u16 BsH[128*64];
  __shared__ u16 BsL[128*64];

  const int tid = threadIdx.x;
  const int w = tid >> 6, l = tid & 63, lm = l & 15, lh = l >> 4;
  const int bm = blockIdx.y << 7, bn = blockIdx.x << 7;
  const int wr = w >> 1, wc = w & 1;

  f32x4 acc[4][4];
#pragma unroll
  for (int i = 0; i < 4; ++i)
#pragma unroll
    for (int j = 0; j < 4; ++j) { f32x4 z = {0.f,0.f,0.f,0.f}; acc[i][j] = z; }

  const int lr8 = l >> 3, sp = l & 7;
  const int ar = tid >> 3, as_ = tid & 7;

  for (int kt = 0; kt < GK; kt += 64) {
    __syncthreads();
#pragma unroll
    for (int c = 0; c < 4; ++c) {
      const int r = (w*4 + c)*8 + lr8;
      const int s = sp ^ (r & 7);
      const u16* gh = Bth + (size_t)(bn + r)*GK + kt + s*8;
      const u16* gl = Btl + (size_t)(bn + r)*GK + kt + s*8;
      __builtin_amdgcn_global_load_lds(
        (const __attribute__((address_space(1))) void*)gh,
        (__attribute__((address_space(3))) void*)(BsH + (w*4 + c)*512), 16, 0, 0);
      __builtin_amdgcn_global_load_lds(
        (const __attribute__((address_space(1))) void*)gl,
        (__attribute__((address_space(3))) void*)(BsL + (w*4 + c)*512), 16, 0, 0);
    }
#pragma unroll
    for (int p = 0; p < 4; ++p) {
      const int r = p*32 + ar;
      const float* gx = x + (size_t)(bm + r)*NEMB + kt + as_*8;
      float4 f0 = *(const float4*)gx;
      float4 f1 = *(const float4*)(gx + 4);
      float fv[8] = {f0.x,f0.y,f0.z,f0.w,f1.x,f1.y,f1.z,f1.w};
      uint4 hq, lq;
      hq.x = cvtpk(fv[0], fv[1]); hq.y = cvtpk(fv[2], fv[3]);
      hq.z = cvtpk(fv[4], fv[5]); hq.w = cvtpk(fv[6], fv[7]);
      float l0 = fv[0] - asf(hq.x << 16), l1 = fv[1] - asf(hq.x & 0xffff0000u);
      float l2 = fv[2] - asf(hq.y << 16), l3 = fv[3] - asf(hq.y & 0xffff0000u);
      float l4 = fv[4] - asf(hq.z << 16), l5 = fv[5] - asf(hq.z & 0xffff0000u);
      float l6 = fv[6] - asf(hq.w << 16), l7 = fv[7] - asf(hq.w & 0xffff0000u);
      lq.x = cvtpk(l0, l1); lq.y = cvtpk(l2, l3);
      lq.z = cvtpk(l4, l5); lq.w = cvtpk(l6, l7);
      const int off = r*64 + (as_ ^ (r & 7))*8;
      *(uint4*)&AsH[off] = hq;
      *(uint4*)&AsL[off] = lq;
    }
    __syncthreads();
#pragma unroll
    for (int kk = 0; kk < 2; ++kk) {
      bf16x8 ah[4], al[4], bh[4], bl[4];
#pragma unroll
      for (int mi = 0; mi < 4; ++mi) {
        int r = wr*64 + mi*16 + lm;
        int s = (kk*4 + lh) ^ (r & 7);
        ah[mi] = *(const bf16x8*)(AsH + r*64 + s*8);
        al[mi] = *(const bf16x8*)(AsL + r*64 + s*8);
      }
#pragma unroll
      for (int nj = 0; nj < 4; ++nj) {
        int r = wc*64 + nj*16 + lm;
        int s = (kk*4 + lh) ^ (r & 7);
        bh[nj] = *(const bf16x8*)(BsH + r*64 + s*8);
        bl[nj] = *(const bf16x8*)(BsL + r*64 + s*8);
      }
#pragma unroll
      for (int mi = 0; mi < 4; ++mi)
#pragma unroll
        for (int nj = 0; nj < 4; ++nj) {
          acc[mi][nj] = __builtin_amdgcn_mfma_f32_16x16x32_bf16(ah[mi], bh[nj], acc[mi][nj], 0,0,0);
          acc[mi][nj] = __builtin_amdgcn_mfma_f32_16x16x32_bf16(al[mi], bh[nj], acc[mi][nj], 0,0,0);
          acc[mi][nj] = __builtin_amdgcn_mfma_f32_16x16x32_bf16(ah[mi], bl[nj], acc[mi][nj], 0,0,0);
        }
    }
  }

  const int colbase = bn + wc*64;
  if (colbase < VOFF) {
    u16* C; int ldcc, cb2;
    if (colbase < KOFF) { C = qb; ldcc = NH*DD;  cb2 = colbase; }
    else                { C = kb; ldcc = NKV*DD; cb2 = colbase - KOFF; }
#pragma unroll
    for (int mi = 0; mi < 4; ++mi) {
#pragma unroll
      for (int r = 0; r < 4; ++r) {
        const int rl = wr*64 + mi*16 + 4*lh + r;
        const int t = (bm + rl) & (TT - 1);
        const float c0 = cosb[t*32 + lm],      s0 = sinb[t*32 + lm];
        const float c1 = cosb[t*32 + 16 + lm], s1 = sinb[t*32 + 16 + lm];
        float o0 = acc[mi][0][r]*c0 - acc[mi][2][r]*s0;
        float o1 = acc[mi][1][r]*c1 - acc[mi][3][r]*s1;
        float o2 = acc[mi][2][r]*c0 + acc[mi][0][r]*s0;
        float o3 = acc[mi][3][r]*c1 + acc[mi][1][r]*s1;
        float ss = o0*o0 + o1*o1 + o2*o2 + o3*o3;
        ss += __shfl_xor(ss, 1); ss += __shfl_xor(ss, 2);
        ss += __shfl_xor(ss, 4); ss += __shfl_xor(ss, 8);
        const float rr = rsqrtf(ss*(1.f/64.f) + 1e-6f);
        u16* dst = C + (size_t)(bm + rl)*ldcc + cb2 + lm;
        dst[0]  = f2bf(o0*rr);
        dst[16] = f2bf(o1*rr);
        dst[32] = f2bf(o2*rr);
        dst[48] = f2bf(o3*rr);
      }
    }
  } else {
    const int cb2 = colbase - VOFF;
#pragma unroll
    for (int mi = 0; mi < 4; ++mi)
#pragma unroll
      for (int nj = 0; nj < 4; ++nj)
#pragma unroll
        for (int r = 0; r < 4; ++r) {
          const int rl = wr*64 + mi*16 + 4*lh + r;
          vb[(size_t)(bm + rl)*(NKV*DD) + cb2 + nj*16 + lm] = acc[mi][nj][r];
        }
  }
}

// ---------------------------------------------------------------------------
// Out GEMM (unchanged, proven R5)
// ---------------------------------------------------------------------------
__global__ void __launch_bounds__(256)
gemm_out(const u16* __restrict__ Ah, const u16* __restrict__ Al,
         const u16* __restrict__ Bth, const u16* __restrict__ Btl,
         float* __restrict__ C)
{
  __shared__ u16 AsH[128*64];
  __shared__ u16 AsL[128*64];
  __shared__ u16 BsH[128*64];
  __shared__ u16 BsL[128*64];
  const int tid = threadIdx.x;
  const int w = tid >> 6, l = tid & 63, lm = l & 15, lh = l >> 4;
  const int bm = blockIdx.y << 7, bn = blockIdx.x << 7;
  const int wr = w >> 1, wc = w & 1;

  f32x4 acc[4][4];
#pragma unroll
  for (int i = 0; i < 4; ++i)
#pragma unroll
    for (int j = 0; j < 4; ++j) { f32x4 z = {0.f,0.f,0.f,0.f}; acc[i][j] = z; }

  const int lr8 = l >> 3, sp = l & 7;
  for (int kt = 0; kt < GK; kt += 64) {
    __syncthreads();
#pragma unroll
    for (int c = 0; c < 4; ++c) {
      const int r = (w*4 + c)*8 + lr8;
      const int s = sp ^ (r & 7);
      const u16* gah = Ah  + (size_t)(bm + r)*(NH*DD) + kt + s*8;
      const u16* gal = Al  + (size_t)(bm + r)*(NH*DD) + kt + s*8;
      const u16* gbh = Bth + (size_t)(bn + r)*GK      + kt + s*8;
      const u16* gbl = Btl + (size_t)(bn + r)*GK      + kt + s*8;
      __builtin_amdgcn_global_load_lds(
        (const __attribute__((address_space(1))) void*)gah,
        (__attribute__((address_space(3))) void*)(AsH + (w*4 + c)*512), 16, 0, 0);
      __builtin_amdgcn_global_load_lds(
        (const __attribute__((address_space(1))) void*)gal,
        (__attribute__((address_space(3))) void*)(AsL + (w*4 + c)*512), 16, 0, 0);
      __builtin_amdgcn_global_load_lds(
        (const __attribute__((address_space(1))) void*)gbh,
        (__attribute__((address_space(3))) void*)(BsH + (w*4 + c)*512), 16, 0, 0);
      __builtin_amdgcn_global_load_lds(
        (const __attribute__((address_space(1))) void*)gbl,
        (__attribute__((address_space(3))) void*)(BsL + (w*4 + c)*512), 16, 0, 0);
    }
    __syncthreads();
#pragma unroll
    for (int kk = 0; kk < 2; ++kk) {
      bf16x8 ah[4], al[4], bh[4], bl[4];
#pragma unroll
      for (int mi = 0; mi < 4; ++mi) {
        int r = wr*64 + mi*16 + lm;
        int s = (kk*4 + lh) ^ (r & 7);
        ah[mi] = *(const bf16x8*)(AsH + r*64 + s*8);
        al[mi] = *(const bf16x8*)(AsL + r*64 + s*8);
      }
#pragma unroll
      for (int nj = 0; nj < 4; ++nj) {
        int r = wc*64 + nj*16 + lm;
        int s = (kk*4 + lh) ^ (r & 7);
        bh[nj] = *(const bf16x8*)(BsH + r*64 + s*8);
        bl[nj] = *(const bf16x8*)(BsL + r*64 + s*8);
      }
#pragma unroll
      for (int mi = 0; mi < 4; ++mi)
#pragma unroll
        for (int nj = 0; nj < 4; ++nj) {
          acc[mi][nj] = __builtin_amdgcn_mfma_f32_16x16x32_bf16(ah[mi], bh[nj], acc[mi][nj], 0,0,0);
          acc[mi][nj] = __builtin_amdgcn_mfma_f32_16x16x32_bf16(al[mi], bh[nj], acc[mi][nj], 0,0,0);
          acc[mi][nj] = __builtin_amdgcn_mfma_f32_16x16x32_bf16(ah[mi], bl[nj], acc[mi][nj], 0,0,0);
        }
    }
  }
#pragma unroll
  for (int mi = 0; mi < 4; ++mi)
#pragma unroll
    for (int nj = 0; nj < 4; ++nj)
#pragma unroll
      for (int r = 0; r < 4; ++r) {
        const int rl = wr*64 + mi*16 + 4*lh + r;
        C[(size_t)(bm + rl)*NEMB + bn + wc*64 + nj*16 + lm] = acc[mi][nj][r];
      }
}

// ---------------------------------------------------------------------------
// eta = softplus(x @ lr_w + lr_b)  (unchanged)
// ---------------------------------------------------------------------------
__global__ void __launch_bounds__(256)
eta_kernel(const float* __restrict__ x, const float* __restrict__ lr_w,
           const float* __restrict__ lr_b, float* __restrict__ etab)
{
  __shared__ float lw[NKV*NEMB];
  const int tid = threadIdx.x;
  for (int idx = tid; idx < NEMB*NKV; idx += 256) {
    int i = idx >> 3, k2 = idx & 7;
    lw[k2*NEMB + i] = lr_w[idx];
  }
  __syncthreads();
  const int w = tid >> 6, lane = tid & 63;
  const size_t tok = (size_t)blockIdx.x*4 + w;
  const float* xr = x + tok*NEMB;
  float acc[8] = {0.f,0.f,0.f,0.f,0.f,0.f,0.f,0.f};
  for (int j = 0; j < 16; ++j) {
    float xv = xr[lane + 64*j];
#pragma unroll
    for (int k2 = 0; k2 < 8; ++k2)
      acc[k2] += xv * lw[k2*NEMB + lane + 64*j];
  }
#pragma unroll
  for (int k2 = 0; k2 < 8; ++k2)
#pragma unroll
    for (int off = 32; off; off >>= 1) acc[k2] += __shfl_xor(acc[k2], off);
  if (lane == 0) {
#pragma unroll
    for (int k2 = 0; k2 < 8; ++k2) {
      float z = acc[k2] + lr_b[k2];
      etab[tok*NKV + k2] = (z > 20.f) ? z : log1pf(expf(z));
    }
  }
}

// ---------------------------------------------------------------------------
// MFMA TTT scan, R10: 2 barriers/chunk. A-waves own W COLUMN slices ->
// colnorm is wave-local (no colp round-trip, no 3rd phase). K^T/Q double-
// buffered so staging overlaps phase2. Numerics identical to R9 (0.082).
// ---------------------------------------------------------------------------
__global__ void __launch_bounds__(512, 1)
scan_mfma(u16* __restrict__ qbuf, u16* __restrict__ ylo,
          const u16* __restrict__ kbuf,
          const float* __restrict__ vbuf, const float* __restrict__ etabuf,
          const float* __restrict__ onw, const float* __restrict__ wis_p)
{
  extern __shared__ char smraw[];
  u16* KbT_A = (u16*)smraw;           // K^T[d][c], buffer A
  u16* KbT_B = KbT_A + 64*ST2;        // buffer B
  u16* Q0_A  = KbT_B + 64*ST2;        // Q_h0[c][d]
  u16* Q0_B  = Q0_A + 64*ST2;
  u16* Q1_A  = Q0_B + 64*ST2;         // Q_h1[c][d]
  u16* Q1_B  = Q1_A + 64*ST2;
  u16* Ab0   = Q1_B + 64*ST2;         // A_h0[ci][cj]
  u16* Ab1   = Ab0 + 64*ST2;          // A_h1[ci][cj]
  u16* EsT   = Ab1 + 64*ST2;          // negEs^T[e][c]
  u16* WbT   = EsT + 64*ST2;          // W^T[e][d]
  float* onws = (float*)(WbT + 64*ST2);

  const int tid = threadIdx.x;
  const int b = blockIdx.x >> 3, kh = blockIdx.x & 7;
  const int w = tid >> 6, l = tid & 63, lm = l & 15, lh = l >> 4;
  const bool gA = (w < 4);
  const int m0 = (w & 3) * 16;        // M-row slice (E rows, out rows, AT rows)
  const int nw = (w & 3);             // A: owned W column block
  const int cb = m0 + lh*4;
  const float wis = *wis_p;

  // A-wave w owns W[:, nw*16+lm] rows m*16+lh*4+r: Wreg[m][r]
  float Wreg[4][4];
  if (gA) {
#pragma unroll
    for (int m = 0; m < 4; ++m) {
      const int e = nw*16 + lm;
#pragma unroll
      for (int r = 0; r < 4; ++r)
        Wreg[m][r] = ((m*16 + lh*4 + r) == e) ? wis : 0.f;
      uint2 u;
      u.x = cvtpk(Wreg[m][0], Wreg[m][1]);
      u.y = cvtpk(Wreg[m][2], Wreg[m][3]);
      *(uint2*)&WbT[e*ST2 + m*16 + lh*4] = u;
    }
  }
  if (tid < 64) onws[tid] = onw[tid];

  const int st = tid & 255;
  const int stc4 = (st >> 4)*4;
  const int std4 = (st & 15)*4;

  ushort4 kpre[4], qpre0[4], qpre1[4];   // B staging regs
  bf16x8 akp0, akp1, ak0, ak1;
  float vpre[4][4], vcur[4][4];          // A
  float epre[4], ecur[4];                // A

#define LOAD_PF(CH)                                                            \
  { const size_t rb = (size_t)b*TT + (size_t)(CH)*64;                          \
    if (!gA) {                                                                 \
      _Pragma("unroll")                                                        \
      for (int i = 0; i < 4; ++i) {                                            \
        kpre[i]  = *(const ushort4*)(kbuf + (rb+stc4+i)*(NKV*DD) + kh*DD + std4);\
        qpre0[i] = *(const ushort4*)(qbuf + (rb+stc4+i)*(NH*DD) + (kh*2)*DD + std4);\
        qpre1[i] = *(const ushort4*)(qbuf + (rb+stc4+i)*(NH*DD) + (kh*2+1)*DD + std4);\
      }                                                                        \
    }                                                                          \
    akp0 = *(const bf16x8*)(kbuf + (rb+m0+lm)*(NKV*DD) + kh*DD + 8*lh);        \
    akp1 = *(const bf16x8*)(kbuf + (rb+m0+lm)*(NKV*DD) + kh*DD + 32 + 8*lh);   \
    if (gA) {                                                                  \
      _Pragma("unroll")                                                        \
      for (int n = 0; n < 4; ++n)                                              \
        _Pragma("unroll")                                                      \
        for (int r = 0; r < 4; ++r)                                            \
          vpre[n][r] = vbuf[(rb+cb+r)*(NKV*DD) + kh*DD + n*16 + lm];           \
      _Pragma("unroll")                                                        \
      for (int r = 0; r < 4; ++r) epre[r] = etabuf[(rb+cb+r)*NKV + kh];        \
    } }

// stage prefetched K/Q into given LDS buffers (B-waves), promote regs (A)
#define PROMOTE(KT, Q0d, Q1d)                                                  \
  { ak0 = akp0; ak1 = akp1;                                                    \
    if (gA) {                                                                  \
      _Pragma("unroll")                                                        \
      for (int n = 0; n < 4; ++n)                                              \
        _Pragma("unroll")                                                      \
        for (int r = 0; r < 4; ++r) vcur[n][r] = vpre[n][r];                   \
      _Pragma("unroll")                                                        \
      for (int r = 0; r < 4; ++r) ecur[r] = epre[r];                           \
    } else {                                                                   \
      ushort4 u;                                                               \
      u.x=kpre[0].x; u.y=kpre[1].x; u.z=kpre[2].x; u.w=kpre[3].x;              \
      *(ushort4*)&(KT)[(std4+0)*ST2 + stc4] = u;                               \
      u.x=kpre[0].y; u.y=kpre[1].y; u.z=kpre[2].y; u.w=kpre[3].y;              \
      *(ushort4*)&(KT)[(std4+1)*ST2 + stc4] = u;                               \
      u.x=kpre[0].z; u.y=kpre[1].z; u.z=kpre[2].z; u.w=kpre[3].z;              \
      *(ushort4*)&(KT)[(std4+2)*ST2 + stc4] = u;                               \
      u.x=kpre[0].w; u.y=kpre[1].w; u.z=kpre[2].w; u.w=kpre[3].w;              \
      *(ushort4*)&(KT)[(std4+3)*ST2 + stc4] = u;                               \
      _Pragma("unroll")                                                        \
      for (int i = 0; i < 4; ++i) {                                            \
        *(ushort4*)&(Q0d)[(stc4+i)*ST2 + std4] = qpre0[i];                     \
        *(ushort4*)&(Q1d)[(stc4+i)*ST2 + std4] = qpre1[i];                     \
      }                                                                        \
    } }

  LOAD_PF(0);
  PROMOTE(KbT_A, Q0_A, Q1_A);
  lds_barrier();

  f32x4 oc[4];
  bf16x8 wfr[8];

  for (int ch = 0; ch < NCH; ++ch) {
    const size_t rowbase = (size_t)b*TT + (size_t)ch*64;
    u16* KbTc = (ch & 1) ? KbT_B : KbT_A;
    u16* KbTn = (ch & 1) ? KbT_A : KbT_B;
    u16* Q0c  = (ch & 1) ? Q0_B : Q0_A;
    u16* Q0n  = (ch & 1) ? Q0_A : Q0_B;
    u16* Q1c  = (ch & 1) ? Q1_B : Q1_A;
    u16* Q1n  = (ch & 1) ? Q1_A : Q1_B;

    if (ch < NCH-1) LOAD_PF(ch+1);

    // ---------------- phase1 ----------------
    if (gA) {
      // E = K·W -> negEs -> EsT;  then out_h0 partial = Q0·W_old
      f32x4 eac[4];
#pragma unroll
      for (int n = 0; n < 4; ++n) { f32x4 z = {0.f,0.f,0.f,0.f}; eac[n] = z; }
      __builtin_amdgcn_s_setprio(1);
#pragma unroll
      for (int n = 0; n < 4; ++n) {
        wfr[2*n]   = ldfrag(WbT, n*16,  0, lm, lh);
        wfr[2*n+1] = ldfrag(WbT, n*16, 32, lm, lh);
        eac[n] = __builtin_amdgcn_mfma_f32_16x16x32_bf16(ak0, wfr[2*n],   eac[n], 0,0,0);
        eac[n] = __builtin_amdgcn_mfma_f32_16x16x32_bf16(ak1, wfr[2*n+1], eac[n], 0,0,0);
      }
      __builtin_amdgcn_s_setprio(0);
#pragma unroll
      for (int n = 0; n < 4; ++n) {
        const int e = n*16 + lm;
        uint2 u;
        u.x = cvtpk(ecur[0]*(vcur[n][0] - eac[n][0]),
                    ecur[1]*(vcur[n][1] - eac[n][1]));
        u.y = cvtpk(ecur[2]*(vcur[n][2] - eac[n][2]),
                    ecur[3]*(vcur[n][3] - eac[n][3]));
        *(uint2*)&EsT[e*ST2 + cb] = u;
      }
      bf16x8 aQ0 = ldfrag(Q0c, m0, 0, lm, lh), aQ1 = ldfrag(Q0c, m0, 32, lm, lh);
      __builtin_amdgcn_s_setprio(1);
#pragma unroll
      for (int n = 0; n < 4; ++n) {
        f32x4 z = {0.f,0.f,0.f,0.f};
        z = __builtin_amdgcn_mfma_f32_16x16x32_bf16(aQ0, wfr[2*n],   z, 0,0,0);
        z = __builtin_amdgcn_mfma_f32_16x16x32_bf16(aQ1, wfr[2*n+1], z, 0,0,0);
        oc[n] = z;
      }
      __builtin_amdgcn_s_setprio(0);
    } else {
      // AT = K·Q^T (both heads) -> Ab0/Ab1; prefetch wfr for phase2 out_h1
      f32x4 a0c[4], a1c[4];
#pragma unroll
      for (int n = 0; n < 4; ++n) { f32x4 z = {0.f,0.f,0.f,0.f}; a0c[n] = z; a1c[n] = z; }
      __builtin_amdgcn_s_setprio(1);
#pragma unroll
      for (int n = 0; n < 4; ++n) {
        a0c[n] = __builtin_amdgcn_mfma_f32_16x16x32_bf16(ak0, ldfrag(Q0c, n*16,  0, lm, lh), a0c[n], 0,0,0);
        a0c[n] = __builtin_amdgcn_mfma_f32_16x16x32_bf16(ak1, ldfrag(Q0c, n*16, 32, lm, lh), a0c[n], 0,0,0);
        a1c[n] = __builtin_amdgcn_mfma_f32_16x16x32_bf16(ak0, ldfrag(Q1c, n*16,  0, lm, lh), a1c[n], 0,0,0);
        a1c[n] = __builtin_amdgcn_mfma_f32_16x16x32_bf16(ak1, ldfrag(Q1c, n*16, 32, lm, lh), a1c[n], 0,0,0);
      }
      __builtin_amdgcn_s_setprio(0);
#pragma unroll
      for (int n = 0; n < 4; ++n) {
        const int ci = n*16 + lm;
        uint2 u0, u1;
        u0.x = cvtpk((cb+0 <= ci) ? a0c[n][0] : 0.f, (cb+1 <= ci) ? a0c[n][1] : 0.f);
        u0.y = cvtpk((cb+2 <= ci) ? a0c[n][2] : 0.f, (cb+3 <= ci) ? a0c[n][3] : 0.f);
        u1.x = cvtpk((cb+0 <= ci) ? a1c[n][0] : 0.f, (cb+1 <= ci) ? a1c[n][1] : 0.f);
        u1.y = cvtpk((cb+2 <= ci) ? a1c[n][2] : 0.f, (cb+3 <= ci) ? a1c[n][3] : 0.f);
        *(uint2*)&Ab0[ci*ST2 + cb] = u0;
        *(uint2*)&Ab1[ci*ST2 + cb] = u1;
      }
#pragma unroll
      for (int n = 0; n < 4; ++n) {
        wfr[2*n]   = ldfrag(WbT, n*16,  0, lm, lh);
        wfr[2*n+1] = ldfrag(WbT, n*16, 32, lm, lh);
      }
    }
    lds_barrier();

    // ---------------- phase2 ----------------
    {
      bf16x8 esf[8];
#pragma unroll
      for (int n = 0; n < 4; ++n) {
        esf[2*n]   = ldfrag(EsT, n*16,  0, lm, lh);
        esf[2*n+1] = ldfrag(EsT, n*16, 32, lm, lh);
      }
      if (gA) {
        // finish out_h0 = Q0·W + A0·negEs
        bf16x8 aA0 = ldfrag(Ab0, m0, 0, lm, lh), aA1 = ldfrag(Ab0, m0, 32, lm, lh);
        __builtin_amdgcn_s_setprio(1);
#pragma unroll
        for (int n = 0; n < 4; ++n) {
          oc[n] = __builtin_amdgcn_mfma_f32_16x16x32_bf16(aA0, esf[2*n],   oc[n], 0,0,0);
          oc[n] = __builtin_amdgcn_mfma_f32_16x16x32_bf16(aA1, esf[2*n+1], oc[n], 0,0,0);
        }
        __builtin_amdgcn_s_setprio(0);
        float rr[4];
#pragma unroll
        for (int r = 0; r < 4; ++r) {
          float s = oc[0][r]*oc[0][r] + oc[1][r]*oc[1][r]
                  + oc[2][r]*oc[2][r] + oc[3][r]*oc[3][r];
          s += __shfl_xor(s, 1); s += __shfl_xor(s, 2);
          s += __shfl_xor(s, 4); s += __shfl_xor(s, 8);
          rr[r] = rsqrtf(s*(1.f/64.f) + 1e-6f);
        }
        const int ho = (kh*2 + 0)*DD;
#pragma unroll
        for (int n = 0; n < 4; ++n) {
          const int e = n*16 + lm;
          const float ow = onws[e];
          float v0 = oc[n][0]*rr[0]*ow, v1 = oc[n][1]*rr[1]*ow;
          float v2 = oc[n][2]*rr[2]*ow, v3 = oc[n][3]*rr[3]*ow;
          unsigned h01 = cvtpk(v0, v1), h23 = cvtpk(v2, v3);
          float l0 = v0 - asf(h01 << 16), l1 = v1 - asf(h01 & 0xffff0000u);
          float l2 = v2 - asf(h23 << 16), l3 = v3 - asf(h23 & 0xffff0000u);
          unsigned q01 = cvtpk(l0, l1), q23 = cvtpk(l2, l3);
          const size_t i0 = (rowbase + cb)*(size_t)(NH*DD) + ho + e;
          qbuf[i0]           = (u16)h01;
          qbuf[i0 + NH*DD]   = (u16)(h01 >> 16);
          qbuf[i0 + 2*NH*DD] = (u16)h23;
          qbuf[i0 + 3*NH*DD] = (u16)(h23 >> 16);
          ylo[i0]            = (u16)q01;
          ylo[i0 + NH*DD]    = (u16)(q01 >> 16);
          ylo[i0 + 2*NH*DD]  = (u16)q23;
          ylo[i0 + 3*NH*DD]  = (u16)(q23 >> 16);
        }
        // U' = K^T·negEs (own column block nw); W += U'/64; wave-local colnorm
        __builtin_amdgcn_s_setprio(1);
        float p = 0.f;
#pragma unroll
        for (int m = 0; m < 4; ++m) {
          bf16x8 aU0 = ldfrag(KbTc, m*16, 0, lm, lh);
          bf16x8 aU1 = ldfrag(KbTc, m*16, 32, lm, lh);
          f32x4 z = {0.f,0.f,0.f,0.f};
          z = __builtin_amdgcn_mfma_f32_16x16x32_bf16(aU0, esf[2*nw],   z, 0,0,0);
          z = __builtin_amdgcn_mfma_f32_16x16x32_bf16(aU1, esf[2*nw+1], z, 0,0,0);
#pragma unroll
          for (int r = 0; r < 4; ++r) {
            Wreg[m][r] += z[r]*(1.f/64.f);
            p += Wreg[m][r]*Wreg[m][r];
          }
        }
        __builtin_amdgcn_s_setprio(0);
        p += __shfl_xor(p, 16);
        p += __shfl_xor(p, 32);
        const float rv = 1.f / fmaxf(sqrtf(p), 1e-12f);
#pragma unroll
        for (int m = 0; m < 4; ++m) {
#pragma unroll
          for (int r = 0; r < 4; ++r) Wreg[m][r] *= rv;
          uint2 u;
          u.x = cvtpk(Wreg[m][0], Wreg[m][1]);
          u.y = cvtpk(Wreg[m][2], Wreg[m][3]);
          *(uint2*)&WbT[(nw*16 + lm)*ST2 + m*16 + lh*4] = u;
        }
      } else {
        // out_h1 = Q1·W + A1·negEs
        bf16x8 aQ0 = ldfrag(Q1c, m0, 0, lm, lh), aQ1 = ldfrag(Q1c, m0, 32, lm, lh);
        bf16x8 aA0 = ldfrag(Ab1, m0, 0, lm, lh), aA1 = ldfrag(Ab1, m0, 32, lm, lh);
        __builtin_amdgcn_s_setprio(1);
#pragma unroll
        for (int n = 0; n < 4; ++n) {
          f32x4 z = {0.f,0.f,0.f,0.f};
          z = __builtin_amdgcn_mfma_f32_16x16x32_bf16(aQ0, wfr[2*n],   z, 0,0,0);
          z = __builtin_amdgcn_mfma_f32_16x16x32_bf16(aQ1, wfr[2*n+1], z, 0,0,0);
          z = __builtin_amdgcn_mfma_f32_16x16x32_bf16(aA0, esf[2*n],   z, 0,0,0);
          z = __builtin_amdgcn_mfma_f32_16x16x32_bf16(aA1, esf[2*n+1], z, 0,0,0);
          oc[n] = z;
        }
        __builtin_amdgcn_s_setprio(0);
        float rr[4];
#pragma unroll
        for (int r = 0; r < 4; ++r) {
          float s = oc[0][r]*oc[0][r] + oc[1][r]*oc[1][r]
                  + oc[2][r]*oc[2][r] + oc[3][r]*oc[3][r];
          s += __shfl_xor(s, 1); s += __shfl_xor(s, 2);
          s += __shfl_xor(s, 4); s += __shfl_xor(s, 8);
          rr[r] = rsqrtf(s*(1.f/64.f) + 1e-6f);
        }
        const int ho = (kh*2 + 1)*DD;
#pragma unroll
        for (int n = 0; n < 4; ++n) {
          const int e = n*16 + lm;
          const float ow = onws[e];
          float v0 = oc[n][0]*rr[0]*ow, v1 = oc[n][1]*rr[1]*ow;
          float v2 = oc[n][2]*rr[2]*ow, v3 = oc[n][3]*rr[3]*ow;
          unsigned h01 = cvtpk(v0, v1), h23 = cvtpk(v2, v3);
          float l0 = v0 - asf(h01 << 16), l1 = v1 - asf(h01 & 0xffff0000u);
          float l2 = v2 - asf(h23 << 16), l3 = v3 - asf(h23 & 0xffff0000u);
          unsigned q01 = cvtpk(l0, l1), q23 = cvtpk(l2, l3);
          const size_t i0 = (rowbase + cb)*(size_t)(NH*DD) + ho + e;
          qbuf[i0]           = (u16)h01;
          qbuf[i0 + NH*DD]   = (u16)(h01 >> 16);
          qbuf[i0 + 2*NH*DD] = (u16)h23;
          qbuf[i0 + 3*NH*DD] = (u16)(h23 >> 16);
          ylo[i0]            = (u16)q01;
          ylo[i0 + NH*DD]    = (u16)(q01 >> 16);
          ylo[i0 + 2*NH*DD]  = (u16)q23;
          ylo[i0 + 3*NH*DD]  = (u16)(q23 >> 16);
        }
        // stage next chunk's K^T/Q into the other buffers
        if (ch < NCH-1) PROMOTE(KbTn, Q0n, Q1n);
      }
      if (gA && ch < NCH-1) PROMOTE(KbTn, Q0n, Q1n);  // A: reg promote only
    }
    lds_barrier();
  }
#undef LOAD_PF
#undef PROMOTE
}

// ---------------------------------------------------------------------------
extern "C" void kernel_launch(void* const* d_in, const int* in_sizes, int n_in,
                              void* d_out, int out_size, void* d_ws, size_t ws_size,
                              hipStream_t stream)
{
  (void)in_sizes; (void)n_in; (void)out_size;
  const float* x    = (const float*)d_in[0];
  const float* cosb = (const float*)d_in[1];
  const float* sinb = (const float*)d_in[2];
  const float* Wq   = (const float*)d_in[3];
  const float* Wk   = (const float*)d_in[4];
  const float* Wv   = (const float*)d_in[5];
  const float* Wo   = (const float*)d_in[6];
  const float* lrw  = (const float*)d_in[7];
  const float* lrb  = (const float*)d_in[8];
  const float* onw  = (const float*)d_in[9];
  const float* wis  = (const float*)d_in[10];
  float* out = (float*)d_out;

  const size_t qN   = (size_t)BTOT*NH*DD;      // u16 (q, later y_hi)
  const size_t kN   = (size_t)BTOT*NKV*DD;     // u16
  const size_t wtN  = (size_t)2048*GK;         // u16 per plane
  const size_t wotN = (size_t)1024*GK;         // u16 per plane
  const size_t vN   = (size_t)BTOT*NKV*DD;     // f32
  const size_t etaN = (size_t)BTOT*NKV;        // f32
  const size_t need = (qN*2 + kN + wtN*2 + wotN*2)*2 + (vN + etaN)*4;
  if (ws_size < need) return;

  u16* qbuf  = (u16*)d_ws;          // q, then y_hi
  u16* ylo   = qbuf + qN;           // y_lo
  u16* kbuf  = ylo + qN;
  u16* wth   = kbuf + kN;
  u16* wtl   = wth + wtN;
  u16* woth  = wtl + wtN;
  u16* wotl  = woth + wotN;
  float* vbuf = (float*)(wotl + wotN);
  float* etab = vbuf + vN;

  wt_split<<<dim3(16,16), 256, 0, stream>>>(Wq, wth,           wtl,           NH*DD);
  wt_split<<<dim3( 8,16), 256, 0, stream>>>(Wk, wth + 1024*GK, wtl + 1024*GK, NKV*DD);
  wt_split<<<dim3( 8,16), 256, 0, stream>>>(Wv, wth + 1536*GK, wtl + 1536*GK, NKV*DD);
  wt_split<<<dim3(16,16), 256, 0, stream>>>(Wo, woth,          wotl,          NEMB);

  gemm_qkv<<<dim3(16,128), 256, 0, stream>>>(x, wth, wtl, qbuf, kbuf, vbuf, cosb, sinb);
  eta_kernel<<<BTOT/4, 256, 0, stream>>>(x, lrw, lrb, etab);

  const size_t SMEM = (size_t)(10*64*ST2)*2 + (size_t)64*4;  // 102656 B
  hipFuncSetAttribute(reinterpret_cast<const void*>(scan_mfma),
                      hipFuncAttributeMaxDynamicSharedMemorySize, (int)SMEM);
  scan_mfma<<<32, 512, SMEM, stream>>>(qbuf, ylo, kbuf, vbuf, etab, onw, wis);

  gemm_out<<<dim3(8,128), 256, 0, stream>>>(qbuf, ylo, woth, wotl, out);
}

// Round 11
// 662.966 us; speedup vs baseline: 1.0293x; 1.0293x over previous
//
#include <hip/hip_runtime.h>
#include <math.h>

#define BB 4
#define TT 4096
#define NEMB 1024
#define NH 16
#define NKV 8
#define DD 64
#define NCH 64
#define BTOT (BB*TT)
#define KOFF 1024
#define VOFF 1536
#define GK 1024
#define ST2 80   // bf16 LDS row stride: 160B; balanced bank map

typedef __attribute__((ext_vector_type(8))) __bf16 bf16x8;
typedef __attribute__((ext_vector_type(4))) float f32x4;
typedef unsigned short u16;

__device__ inline u16 f2bf(float f){
  union { float f; unsigned u; } x; x.f = f;
  unsigned r = x.u + 0x7fffu + ((x.u >> 16) & 1u);
  return (u16)(r >> 16);
}
__device__ inline float bf2f(u16 u){
  union { unsigned u; float f; } x; x.u = ((unsigned)u) << 16; return x.f;
}
__device__ inline float asf(unsigned u){
  union { unsigned u; float f; } x; x.u = u; return x.f;
}
// HW RTNE pack: low16 = bf16(a), high16 = bf16(b)
__device__ inline unsigned cvtpk(float a, float b){
  unsigned r;
  asm("v_cvt_pk_bf16_f32 %0, %1, %2" : "=v"(r) : "v"(a), "v"(b));
  return r;
}
__device__ inline bf16x8 ldfrag(const u16* a, int outer, int k0, int lm, int lh){
  return *(const bf16x8*)(a + (size_t)(outer + lm)*ST2 + k0 + 8*lh);
}
// Barrier draining only LDS (lgkmcnt), not global traffic.
__device__ inline void lds_barrier(){
  __builtin_amdgcn_sched_barrier(0);
  asm volatile("s_waitcnt lgkmcnt(0)" ::: "memory");
  __builtin_amdgcn_s_barrier();
  __builtin_amdgcn_sched_barrier(0);
}

// ---------------------------------------------------------------------------
// Weight transpose + hi/lo bf16 split (unchanged, proven R5)
// ---------------------------------------------------------------------------
__global__ void __launch_bounds__(256)
wt_split(const float* __restrict__ src, u16* __restrict__ dsth,
         u16* __restrict__ dstl, int N)
{
  __shared__ float ts[64][68];
  const int tid = threadIdx.x;
  const int n0 = blockIdx.x*64, k0 = blockIdx.y*64;
  const int tx = tid & 15, ty = tid >> 4;
#pragma unroll
  for (int i = 0; i < 4; ++i) {
    int k = ty + i*16;
    float4 v = *(const float4*)(src + (size_t)(k0+k)*N + n0 + tx*4);
    ts[k][tx*4+0]=v.x; ts[k][tx*4+1]=v.y; ts[k][tx*4+2]=v.z; ts[k][tx*4+3]=v.w;
  }
  __syncthreads();
#pragma unroll
  for (int i = 0; i < 4; ++i) {
    int n = ty + i*16;
    ushort4 uh, ul;
    float f0 = ts[tx*4+0][n], f1 = ts[tx*4+1][n];
    float f2 = ts[tx*4+2][n], f3 = ts[tx*4+3][n];
    uh.x = f2bf(f0); ul.x = f2bf(f0 - bf2f(uh.x));
    uh.y = f2bf(f1); ul.y = f2bf(f1 - bf2f(uh.y));
    uh.z = f2bf(f2); ul.z = f2bf(f2 - bf2f(uh.z));
    uh.w = f2bf(f3); ul.w = f2bf(f3 - bf2f(uh.w));
    *(ushort4*)(dsth + (size_t)(n0+n)*GK + k0 + tx*4) = uh;
    *(ushort4*)(dstl + (size_t)(n0+n)*GK + k0 + tx*4) = ul;
  }
}

// ---------------------------------------------------------------------------
// QKV GEMM (unchanged from R8/R9)
// ---------------------------------------------------------------------------
__global__ void __launch_bounds__(256)
gemm_qkv(const float* __restrict__ x,
         const u16* __restrict__ Bth, const u16* __restrict__ Btl,
         u16* __restrict__ qb, u16* __restrict__ kb, float* __restrict__ vb,
         const float* __restrict__ cosb, const float* __restrict__ sinb)
{
  __shared__ u16 AsH[128*64];
  __shared__ u16 AsL[128*64];
  __shared__ u16 BsH[128*64];
  __shared__ u16 BsL[128*64];

  const int tid = threadIdx.x;
  const int w = tid >> 6, l = tid & 63, lm = l & 15, lh = l >> 4;
  const int bm = blockIdx.y << 7, bn = blockIdx.x << 7;
  const int wr = w >> 1, wc = w & 1;

  f32x4 acc[4][4];
#pragma unroll
  for (int i = 0; i < 4; ++i)
#pragma unroll
    for (int j = 0; j < 4; ++j) { f32x4 z = {0.f,0.f,0.f,0.f}; acc[i][j] = z; }

  const int lr8 = l >> 3, sp = l & 7;
  const int ar = tid >> 3, as_ = tid & 7;

  for (int kt = 0; kt < GK; kt += 64) {
    __syncthreads();
#pragma unroll
    for (int c = 0; c < 4; ++c) {
      const int r = (w*4 + c)*8 + lr8;
      const int s = sp ^ (r & 7);
      const u16* gh = Bth + (size_t)(bn + r)*GK + kt + s*8;
      const u16* gl = Btl + (size_t)(bn + r)*GK + kt + s*8;
      __builtin_amdgcn_global_load_lds(
        (const __attribute__((address_space(1))) void*)gh,
        (__attribute__((address_space(3))) void*)(BsH + (w*4 + c)*512), 16, 0, 0);
      __builtin_amdgcn_global_load_lds(
        (const __attribute__((address_space(1))) void*)gl,
        (__attribute__((address_space(3))) void*)(BsL + (w*4 + c)*512), 16, 0, 0);
    }
#pragma unroll
    for (int p = 0; p < 4; ++p) {
      const int r = p*32 + ar;
      const float* gx = x + (size_t)(bm + r)*NEMB + kt + as_*8;
      float4 f0 = *(const float4*)gx;
      float4 f1 = *(const float4*)(gx + 4);
      float fv[8] = {f0.x,f0.y,f0.z,f0.w,f1.x,f1.y,f1.z,f1.w};
      uint4 hq, lq;
      hq.x = cvtpk(fv[0], fv[1]); hq.y = cvtpk(fv[2], fv[3]);
      hq.z = cvtpk(fv[4], fv[5]); hq.w = cvtpk(fv[6], fv[7]);
      float l0 = fv[0] - asf(hq.x << 16), l1 = fv[1] - asf(hq.x & 0xffff0000u);
      float l2 = fv[2] - asf(hq.y << 16), l3 = fv[3] - asf(hq.y & 0xffff0000u);
      float l4 = fv[4] - asf(hq.z << 16), l5 = fv[5] - asf(hq.z & 0xffff0000u);
      float l6 = fv[6] - asf(hq.w << 16), l7 = fv[7] - asf(hq.w & 0xffff0000u);
      lq.x = cvtpk(l0, l1); lq.y = cvtpk(l2, l3);
      lq.z = cvtpk(l4, l5); lq.w = cvtpk(l6, l7);
      const int off = r*64 + (as_ ^ (r & 7))*8;
      *(uint4*)&AsH[off] = hq;
      *(uint4*)&AsL[off] = lq;
    }
    __syncthreads();
#pragma unroll
    for (int kk = 0; kk < 2; ++kk) {
      bf16x8 ah[4], al[4], bh[4], bl[4];
#pragma unroll
      for (int mi = 0; mi < 4; ++mi) {
        int r = wr*64 + mi*16 + lm;
        int s = (kk*4 + lh) ^ (r & 7);
        ah[mi] = *(const bf16x8*)(AsH + r*64 + s*8);
        al[mi] = *(const bf16x8*)(AsL + r*64 + s*8);
      }
#pragma unroll
      for (int nj = 0; nj < 4; ++nj) {
        int r = wc*64 + nj*16 + lm;
        int s = (kk*4 + lh) ^ (r & 7);
        bh[nj] = *(const bf16x8*)(BsH + r*64 + s*8);
        bl[nj] = *(const bf16x8*)(BsL + r*64 + s*8);
      }
#pragma unroll
      for (int mi = 0; mi < 4; ++mi)
#pragma unroll
        for (int nj = 0; nj < 4; ++nj) {
          acc[mi][nj] = __builtin_amdgcn_mfma_f32_16x16x32_bf16(ah[mi], bh[nj], acc[mi][nj], 0,0,0);
          acc[mi][nj] = __builtin_amdgcn_mfma_f32_16x16x32_bf16(al[mi], bh[nj], acc[mi][nj], 0,0,0);
          acc[mi][nj] = __builtin_amdgcn_mfma_f32_16x16x32_bf16(ah[mi], bl[nj], acc[mi][nj], 0,0,0);
        }
    }
  }

  const int colbase = bn + wc*64;
  if (colbase < VOFF) {
    u16* C; int ldcc, cb2;
    if (colbase < KOFF) { C = qb; ldcc = NH*DD;  cb2 = colbase; }
    else                { C = kb; ldcc = NKV*DD; cb2 = colbase - KOFF; }
#pragma unroll
    for (int mi = 0; mi < 4; ++mi) {
#pragma unroll
      for (int r = 0; r < 4; ++r) {
        const int rl = wr*64 + mi*16 + 4*lh + r;
        const int t = (bm + rl) & (TT - 1);
        const float c0 = cosb[t*32 + lm],      s0 = sinb[t*32 + lm];
        const float c1 = cosb[t*32 + 16 + lm], s1 = sinb[t*32 + 16 + lm];
        float o0 = acc[mi][0][r]*c0 - acc[mi][2][r]*s0;
        float o1 = acc[mi][1][r]*c1 - acc[mi][3][r]*s1;
        float o2 = acc[mi][2][r]*c0 + acc[mi][0][r]*s0;
        float o3 = acc[mi][3][r]*c1 + acc[mi][1][r]*s1;
        float ss = o0*o0 + o1*o1 + o2*o2 + o3*o3;
        ss += __shfl_xor(ss, 1); ss += __shfl_xor(ss, 2);
        ss += __shfl_xor(ss, 4); ss += __shfl_xor(ss, 8);
        const float rr = rsqrtf(ss*(1.f/64.f) + 1e-6f);
        u16* dst = C + (size_t)(bm + rl)*ldcc + cb2 + lm;
        dst[0]  = f2bf(o0*rr);
        dst[16] = f2bf(o1*rr);
        dst[32] = f2bf(o2*rr);
        dst[48] = f2bf(o3*rr);
      }
    }
  } else {
    const int cb2 = colbase - VOFF;
#pragma unroll
    for (int mi = 0; mi < 4; ++mi)
#pragma unroll
      for (int nj = 0; nj < 4; ++nj)
#pragma unroll
        for (int r = 0; r < 4; ++r) {
          const int rl = wr*64 + mi*16 + 4*lh + r;
          vb[(size_t)(bm + rl)*(NKV*DD) + cb2 + nj*16 + lm] = acc[mi][nj][r];
        }
  }
}

// ---------------------------------------------------------------------------
// Out GEMM (unchanged, proven R5)
// ---------------------------------------------------------------------------
__global__ void __launch_bounds__(256)
gemm_out(const u16* __restrict__ Ah, const u16* __restrict__ Al,
         const u16* __restrict__ Bth, const u16* __restrict__ Btl,
         float* __restrict__ C)
{
  __shared__ u16 AsH[128*64];
  __shared__ u16 AsL[128*64];
  __shared__ u16 BsH[128*64];
  __shared__ u16 BsL[128*64];
  const int tid = threadIdx.x;
  const int w = tid >> 6, l = tid & 63, lm = l & 15, lh = l >> 4;
  const int bm = blockIdx.y << 7, bn = blockIdx.x << 7;
  const int wr = w >> 1, wc = w & 1;

  f32x4 acc[4][4];
#pragma unroll
  for (int i = 0; i < 4; ++i)
#pragma unroll
    for (int j = 0; j < 4; ++j) { f32x4 z = {0.f,0.f,0.f,0.f}; acc[i][j] = z; }

  const int lr8 = l >> 3, sp = l & 7;
  for (int kt = 0; kt < GK; kt += 64) {
    __syncthreads();
#pragma unroll
    for (int c = 0; c < 4; ++c) {
      const int r = (w*4 + c)*8 + lr8;
      const int s = sp ^ (r & 7);
      const u16* gah = Ah  + (size_t)(bm + r)*(NH*DD) + kt + s*8;
      const u16* gal = Al  + (size_t)(bm + r)*(NH*DD) + kt + s*8;
      const u16* gbh = Bth + (size_t)(bn + r)*GK      + kt + s*8;
      const u16* gbl = Btl + (size_t)(bn + r)*GK      + kt + s*8;
      __builtin_amdgcn_global_load_lds(
        (const __attribute__((address_space(1))) void*)gah,
        (__attribute__((address_space(3))) void*)(AsH + (w*4 + c)*512), 16, 0, 0);
      __builtin_amdgcn_global_load_lds(
        (const __attribute__((address_space(1))) void*)gal,
        (__attribute__((address_space(3))) void*)(AsL + (w*4 + c)*512), 16, 0, 0);
      __builtin_amdgcn_global_load_lds(
        (const __attribute__((address_space(1))) void*)gbh,
        (__attribute__((address_space(3))) void*)(BsH + (w*4 + c)*512), 16, 0, 0);
      __builtin_amdgcn_global_load_lds(
        (const __attribute__((address_space(1))) void*)gbl,
        (__attribute__((address_space(3))) void*)(BsL + (w*4 + c)*512), 16, 0, 0);
    }
    __syncthreads();
#pragma unroll
    for (int kk = 0; kk < 2; ++kk) {
      bf16x8 ah[4], al[4], bh[4], bl[4];
#pragma unroll
      for (int mi = 0; mi < 4; ++mi) {
        int r = wr*64 + mi*16 + lm;
        int s = (kk*4 + lh) ^ (r & 7);
        ah[mi] = *(const bf16x8*)(AsH + r*64 + s*8);
        al[mi] = *(const bf16x8*)(AsL + r*64 + s*8);
      }
#pragma unroll
      for (int nj = 0; nj < 4; ++nj) {
        int r = wc*64 + nj*16 + lm;
        int s = (kk*4 + lh) ^ (r & 7);
        bh[nj] = *(const bf16x8*)(BsH + r*64 + s*8);
        bl[nj] = *(const bf16x8*)(BsL + r*64 + s*8);
      }
#pragma unroll
      for (int mi = 0; mi < 4; ++mi)
#pragma unroll
        for (int nj = 0; nj < 4; ++nj) {
          acc[mi][nj] = __builtin_amdgcn_mfma_f32_16x16x32_bf16(ah[mi], bh[nj], acc[mi][nj], 0,0,0);
          acc[mi][nj] = __builtin_amdgcn_mfma_f32_16x16x32_bf16(al[mi], bh[nj], acc[mi][nj], 0,0,0);
          acc[mi][nj] = __builtin_amdgcn_mfma_f32_16x16x32_bf16(ah[mi], bl[nj], acc[mi][nj], 0,0,0);
        }
    }
  }
#pragma unroll
  for (int mi = 0; mi < 4; ++mi)
#pragma unroll
    for (int nj = 0; nj < 4; ++nj)
#pragma unroll
      for (int r = 0; r < 4; ++r) {
        const int rl = wr*64 + mi*16 + 4*lh + r;
        C[(size_t)(bm + rl)*NEMB + bn + wc*64 + nj*16 + lm] = acc[mi][nj][r];
      }
}

// ---------------------------------------------------------------------------
// eta = softplus(x @ lr_w + lr_b)  (unchanged)
// ---------------------------------------------------------------------------
__global__ void __launch_bounds__(256)
eta_kernel(const float* __restrict__ x, const float* __restrict__ lr_w,
           const float* __restrict__ lr_b, float* __restrict__ etab)
{
  __shared__ float lw[NKV*NEMB];
  const int tid = threadIdx.x;
  for (int idx = tid; idx < NEMB*NKV; idx += 256) {
    int i = idx >> 3, k2 = idx & 7;
    lw[k2*NEMB + i] = lr_w[idx];
  }
  __syncthreads();
  const int w = tid >> 6, lane = tid & 63;
  const size_t tok = (size_t)blockIdx.x*4 + w;
  const float* xr = x + tok*NEMB;
  float acc[8] = {0.f,0.f,0.f,0.f,0.f,0.f,0.f,0.f};
  for (int j = 0; j < 16; ++j) {
    float xv = xr[lane + 64*j];
#pragma unroll
    for (int k2 = 0; k2 < 8; ++k2)
      acc[k2] += xv * lw[k2*NEMB + lane + 64*j];
  }
#pragma unroll
  for (int k2 = 0; k2 < 8; ++k2)
#pragma unroll
    for (int off = 32; off; off >>= 1) acc[k2] += __shfl_xor(acc[k2], off);
  if (lane == 0) {
#pragma unroll
    for (int k2 = 0; k2 < 8; ++k2) {
      float z = acc[k2] + lr_b[k2];
      etab[tok*NKV + k2] = (z > 20.f) ? z : log1pf(expf(z));
    }
  }
}

// ---------------------------------------------------------------------------
// MFMA TTT scan, R11 = R9 + ALIAS FIX: q-reads via const qsrc, y-writes via
// yhi — distinct restrict pointers over the same allocation (accesses to any
// address are >=2 iterations apart; the asm memory fences in lds_barrier
// block cross-iteration reordering). Removes the compiler's conservative
// store->load vmcnt serialization between y-stores and q-prefetch.
// Numerics identical to R9 (0.082).
// ---------------------------------------------------------------------------
__global__ void __launch_bounds__(512, 2)
scan_mfma(const u16* __restrict__ qsrc, u16* __restrict__ yhi,
          u16* __restrict__ ylo,
          const u16* __restrict__ kbuf,
          const float* __restrict__ vbuf, const float* __restrict__ etabuf,
          const float* __restrict__ onw, const float* __restrict__ wis_p)
{
  extern __shared__ char smraw[];
  u16* KbT = (u16*)smraw;             // [64][ST2] K^T[d][c]
  u16* Qb0 = KbT + 64*ST2;            // [64][ST2] Q_h0[c][d]
  u16* Qb1 = Qb0 + 64*ST2;            // [64][ST2] Q_h1[c][d]
  u16* Ab0 = Qb1 + 64*ST2;            // [64][ST2] A_h0[ci][cj]
  u16* Ab1 = Ab0 + 64*ST2;            // [64][ST2] A_h1[ci][cj]
  u16* EsT = Ab1 + 64*ST2;            // [64][ST2] negEs^T[e][c]
  u16* WbT = EsT + 64*ST2;            // [64][ST2] W^T[e][d] bf16
  float* colp = (float*)(WbT + 64*ST2); // [64][4]
  float* onws = colp + 64*4;          // [64]

  const int tid = threadIdx.x;
  const int b = blockIdx.x >> 3, kh = blockIdx.x & 7;
  const int w = tid >> 6, l = tid & 63, lm = l & 15, lh = l >> 4;
  const bool gA = (w < 4);
  const int m0 = (w & 3) * 16;
  const int cb = m0 + lh*4;
  const float wis = *wis_p;

  float Wreg[4][4];   // A-group only
  if (gA) {
#pragma unroll
    for (int n = 0; n < 4; ++n) {
      const int e = n*16 + lm;
#pragma unroll
      for (int r = 0; r < 4; ++r)
        Wreg[n][r] = ((cb + r) == e) ? wis : 0.f;
      uint2 u;
      u.x = cvtpk(Wreg[n][0], Wreg[n][1]);
      u.y = cvtpk(Wreg[n][2], Wreg[n][3]);
      *(uint2*)&WbT[e*ST2 + cb] = u;
    }
  }
  if (tid < 64) onws[tid] = onw[tid];

  const int st = tid & 255;           // staging index within group B
  const int stc4 = (st >> 4)*4;
  const int std4 = (st & 15)*4;

  ushort4 kpre[4], qpre0[4], qpre1[4];   // group B staging regs
  bf16x8 akp0, akp1, ak0, ak1;           // all waves
  float vpre[4][4], vcur[4][4];          // group A
  float epre[4], ecur[4];                // group A
  float val[4][4];                       // deferred y (both groups)

#define LOAD_PF(CH)                                                            \
  { const size_t rb = (size_t)b*TT + (size_t)(CH)*64;                          \
    if (!gA) {                                                                 \
      _Pragma("unroll")                                                        \
      for (int i = 0; i < 4; ++i) {                                            \
        kpre[i]  = *(const ushort4*)(kbuf + (rb+stc4+i)*(NKV*DD) + kh*DD + std4);\
        qpre0[i] = *(const ushort4*)(qsrc + (rb+stc4+i)*(NH*DD) + (kh*2)*DD + std4);\
        qpre1[i] = *(const ushort4*)(qsrc + (rb+stc4+i)*(NH*DD) + (kh*2+1)*DD + std4);\
      }                                                                        \
    }                                                                          \
    akp0 = *(const bf16x8*)(kbuf + (rb+m0+lm)*(NKV*DD) + kh*DD + 8*lh);        \
    akp1 = *(const bf16x8*)(kbuf + (rb+m0+lm)*(NKV*DD) + kh*DD + 32 + 8*lh);   \
    if (gA) {                                                                  \
      _Pragma("unroll")                                                        \
      for (int n = 0; n < 4; ++n)                                              \
        _Pragma("unroll")                                                      \
        for (int r = 0; r < 4; ++r)                                            \
          vpre[n][r] = vbuf[(rb+cb+r)*(NKV*DD) + kh*DD + n*16 + lm];           \
      _Pragma("unroll")                                                        \
      for (int r = 0; r < 4; ++r) epre[r] = etabuf[(rb+cb+r)*NKV + kh];        \
    } }

#define PROMOTE()                                                              \
  { ak0 = akp0; ak1 = akp1;                                                    \
    if (gA) {                                                                  \
      _Pragma("unroll")                                                        \
      for (int n = 0; n < 4; ++n)                                              \
        _Pragma("unroll")                                                      \
        for (int r = 0; r < 4; ++r) vcur[n][r] = vpre[n][r];                   \
      _Pragma("unroll")                                                        \
      for (int r = 0; r < 4; ++r) ecur[r] = epre[r];                           \
    } else {                                                                   \
      ushort4 u;                                                               \
      u.x=kpre[0].x; u.y=kpre[1].x; u.z=kpre[2].x; u.w=kpre[3].x;              \
      *(ushort4*)&KbT[(std4+0)*ST2 + stc4] = u;                                \
      u.x=kpre[0].y; u.y=kpre[1].y; u.z=kpre[2].y; u.w=kpre[3].y;              \
      *(ushort4*)&KbT[(std4+1)*ST2 + stc4] = u;                                \
      u.x=kpre[0].z; u.y=kpre[1].z; u.z=kpre[2].z; u.w=kpre[3].z;              \
      *(ushort4*)&KbT[(std4+2)*ST2 + stc4] = u;                                \
      u.x=kpre[0].w; u.y=kpre[1].w; u.z=kpre[2].w; u.w=kpre[3].w;              \
      *(ushort4*)&KbT[(std4+3)*ST2 + stc4] = u;                                \
      _Pragma("unroll")                                                        \
      for (int i = 0; i < 4; ++i) {                                            \
        *(ushort4*)&Qb0[(stc4+i)*ST2 + std4] = qpre0[i];                       \
        *(ushort4*)&Qb1[(stc4+i)*ST2 + std4] = qpre1[i];                       \
      }                                                                        \
    } }

#define STORE_Y(RB)                                                            \
  { const int ho = (kh*2 + (gA ? 0 : 1))*DD;                                   \
    _Pragma("unroll")                                                          \
    for (int n = 0; n < 4; ++n) {                                              \
      const int e = n*16 + lm;                                                 \
      unsigned h01 = cvtpk(val[n][0], val[n][1]);                              \
      unsigned h23 = cvtpk(val[n][2], val[n][3]);                              \
      float l0 = val[n][0] - asf(h01 << 16);                                   \
      float l1 = val[n][1] - asf(h01 & 0xffff0000u);                           \
      float l2 = val[n][2] - asf(h23 << 16);                                   \
      float l3 = val[n][3] - asf(h23 & 0xffff0000u);                           \
      unsigned q01 = cvtpk(l0, l1), q23 = cvtpk(l2, l3);                       \
      const size_t i0 = ((RB) + cb)*(size_t)(NH*DD) + ho + e;                  \
      yhi[i0]           = (u16)h01;                                            \
      yhi[i0 + NH*DD]   = (u16)(h01 >> 16);                                    \
      yhi[i0 + 2*NH*DD] = (u16)h23;                                            \
      yhi[i0 + 3*NH*DD] = (u16)(h23 >> 16);                                    \
      ylo[i0]            = (u16)q01;                                           \
      ylo[i0 + NH*DD]    = (u16)(q01 >> 16);                                   \
      ylo[i0 + 2*NH*DD]  = (u16)q23;                                           \
      ylo[i0 + 3*NH*DD]  = (u16)(q23 >> 16);                                   \
    } }

  LOAD_PF(0);
  PROMOTE();
  lds_barrier();

  f32x4 oc[4];
  bf16x8 wfr[8];

  for (int ch = 0; ch < NCH; ++ch) {
    const size_t rowbase = (size_t)b*TT + (size_t)ch*64;

    if (ch < NCH-1) LOAD_PF(ch+1);
    if (ch > 0) STORE_Y(rowbase - 64);   // prev chunk's y; never blocks

    // ---------------- phase1 ----------------
    if (gA) {
      // E = K·W -> Es; then Q0·W partial for out_h0
      f32x4 eac[4];
#pragma unroll
      for (int n = 0; n < 4; ++n) { f32x4 z = {0.f,0.f,0.f,0.f}; eac[n] = z; }
      __builtin_amdgcn_s_setprio(1);
#pragma unroll
      for (int n = 0; n < 4; ++n) {
        wfr[2*n]   = ldfrag(WbT, n*16,  0, lm, lh);
        wfr[2*n+1] = ldfrag(WbT, n*16, 32, lm, lh);
        eac[n] = __builtin_amdgcn_mfma_f32_16x16x32_bf16(ak0, wfr[2*n],   eac[n], 0,0,0);
        eac[n] = __builtin_amdgcn_mfma_f32_16x16x32_bf16(ak1, wfr[2*n+1], eac[n], 0,0,0);
      }
      __builtin_amdgcn_s_setprio(0);
#pragma unroll
      for (int n = 0; n < 4; ++n) {
        const int e = n*16 + lm;
        uint2 u;
        u.x = cvtpk(ecur[0]*(vcur[n][0] - eac[n][0]),
                    ecur[1]*(vcur[n][1] - eac[n][1]));
        u.y = cvtpk(ecur[2]*(vcur[n][2] - eac[n][2]),
                    ecur[3]*(vcur[n][3] - eac[n][3]));
        *(uint2*)&EsT[e*ST2 + cb] = u;
      }
      bf16x8 aQ0 = ldfrag(Qb0, m0, 0, lm, lh), aQ1 = ldfrag(Qb0, m0, 32, lm, lh);
      __builtin_amdgcn_s_setprio(1);
#pragma unroll
      for (int n = 0; n < 4; ++n) {
        f32x4 z = {0.f,0.f,0.f,0.f};
        z = __builtin_amdgcn_mfma_f32_16x16x32_bf16(aQ0, wfr[2*n],   z, 0,0,0);
        z = __builtin_amdgcn_mfma_f32_16x16x32_bf16(aQ1, wfr[2*n+1], z, 0,0,0);
        oc[n] = z;
      }
      __builtin_amdgcn_s_setprio(0);
    } else {
      // AT = K·Q^T both heads; mask tril -> Ab0/Ab1; prefetch wfr for phase2
      f32x4 a0c[4], a1c[4];
#pragma unroll
      for (int n = 0; n < 4; ++n) { f32x4 z = {0.f,0.f,0.f,0.f}; a0c[n] = z; a1c[n] = z; }
      __builtin_amdgcn_s_setprio(1);
#pragma unroll
      for (int n = 0; n < 4; ++n) {
        a0c[n] = __builtin_amdgcn_mfma_f32_16x16x32_bf16(ak0, ldfrag(Qb0, n*16,  0, lm, lh), a0c[n], 0,0,0);
        a0c[n] = __builtin_amdgcn_mfma_f32_16x16x32_bf16(ak1, ldfrag(Qb0, n*16, 32, lm, lh), a0c[n], 0,0,0);
        a1c[n] = __builtin_amdgcn_mfma_f32_16x16x32_bf16(ak0, ldfrag(Qb1, n*16,  0, lm, lh), a1c[n], 0,0,0);
        a1c[n] = __builtin_amdgcn_mfma_f32_16x16x32_bf16(ak1, ldfrag(Qb1, n*16, 32, lm, lh), a1c[n], 0,0,0);
      }
      __builtin_amdgcn_s_setprio(0);
#pragma unroll
      for (int n = 0; n < 4; ++n) {
        const int ci = n*16 + lm;
        uint2 u0, u1;
        u0.x = cvtpk((cb+0 <= ci) ? a0c[n][0] : 0.f, (cb+1 <= ci) ? a0c[n][1] : 0.f);
        u0.y = cvtpk((cb+2 <= ci) ? a0c[n][2] : 0.f, (cb+3 <= ci) ? a0c[n][3] : 0.f);
        u1.x = cvtpk((cb+0 <= ci) ? a1c[n][0] : 0.f, (cb+1 <= ci) ? a1c[n][1] : 0.f);
        u1.y = cvtpk((cb+2 <= ci) ? a1c[n][2] : 0.f, (cb+3 <= ci) ? a1c[n][3] : 0.f);
        *(uint2*)&Ab0[ci*ST2 + cb] = u0;
        *(uint2*)&Ab1[ci*ST2 + cb] = u1;
      }
#pragma unroll
      for (int n = 0; n < 4; ++n) {
        wfr[2*n]   = ldfrag(WbT, n*16,  0, lm, lh);
        wfr[2*n+1] = ldfrag(WbT, n*16, 32, lm, lh);
      }
    }
    lds_barrier();

    // ---------------- phase2 ----------------
    {
      bf16x8 esf[8];
#pragma unroll
      for (int n = 0; n < 4; ++n) {
        esf[2*n]   = ldfrag(EsT, n*16,  0, lm, lh);
        esf[2*n+1] = ldfrag(EsT, n*16, 32, lm, lh);
      }
      if (gA) {
        bf16x8 aA0 = ldfrag(Ab0, m0, 0, lm, lh), aA1 = ldfrag(Ab0, m0, 32, lm, lh);
        __builtin_amdgcn_s_setprio(1);
#pragma unroll
        for (int n = 0; n < 4; ++n) {
          oc[n] = __builtin_amdgcn_mfma_f32_16x16x32_bf16(aA0, esf[2*n],   oc[n], 0,0,0);
          oc[n] = __builtin_amdgcn_mfma_f32_16x16x32_bf16(aA1, esf[2*n+1], oc[n], 0,0,0);
        }
        __builtin_amdgcn_s_setprio(0);
        float rr[4];
#pragma unroll
        for (int r = 0; r < 4; ++r) {
          float s = oc[0][r]*oc[0][r] + oc[1][r]*oc[1][r]
                  + oc[2][r]*oc[2][r] + oc[3][r]*oc[3][r];
          s += __shfl_xor(s, 1); s += __shfl_xor(s, 2);
          s += __shfl_xor(s, 4); s += __shfl_xor(s, 8);
          rr[r] = rsqrtf(s*(1.f/64.f) + 1e-6f);
        }
#pragma unroll
        for (int n = 0; n < 4; ++n) {
          const float ow = onws[n*16 + lm];
#pragma unroll
          for (int r = 0; r < 4; ++r) val[n][r] = oc[n][r]*rr[r]*ow;
        }
        // U' = K^T·negEs; W += U'/64; colnorm partials
        bf16x8 aT0 = ldfrag(KbT, m0, 0, lm, lh), aT1 = ldfrag(KbT, m0, 32, lm, lh);
        __builtin_amdgcn_s_setprio(1);
#pragma unroll
        for (int n = 0; n < 4; ++n) {
          f32x4 z = {0.f,0.f,0.f,0.f};
          z = __builtin_amdgcn_mfma_f32_16x16x32_bf16(aT0, esf[2*n],   z, 0,0,0);
          z = __builtin_amdgcn_mfma_f32_16x16x32_bf16(aT1, esf[2*n+1], z, 0,0,0);
          float p = 0.f;
#pragma unroll
          for (int r = 0; r < 4; ++r) {
            Wreg[n][r] += z[r]*(1.f/64.f);
            p += Wreg[n][r]*Wreg[n][r];
          }
          p += __shfl_xor(p, 16);
          p += __shfl_xor(p, 32);
          if (lh == 0) colp[(n*16 + lm)*4 + (w & 3)] = p;
        }
        __builtin_amdgcn_s_setprio(0);
      } else {
        bf16x8 aQ0 = ldfrag(Qb1, m0, 0, lm, lh), aQ1 = ldfrag(Qb1, m0, 32, lm, lh);
        bf16x8 aA0 = ldfrag(Ab1, m0, 0, lm, lh), aA1 = ldfrag(Ab1, m0, 32, lm, lh);
        __builtin_amdgcn_s_setprio(1);
#pragma unroll
        for (int n = 0; n < 4; ++n) {
          f32x4 z = {0.f,0.f,0.f,0.f};
          z = __builtin_amdgcn_mfma_f32_16x16x32_bf16(aQ0, wfr[2*n],   z, 0,0,0);
          z = __builtin_amdgcn_mfma_f32_16x16x32_bf16(aQ1, wfr[2*n+1], z, 0,0,0);
          z = __builtin_amdgcn_mfma_f32_16x16x32_bf16(aA0, esf[2*n],   z, 0,0,0);
          z = __builtin_amdgcn_mfma_f32_16x16x32_bf16(aA1, esf[2*n+1], z, 0,0,0);
          oc[n] = z;
        }
        __builtin_amdgcn_s_setprio(0);
        float rr[4];
#pragma unroll
        for (int r = 0; r < 4; ++r) {
          float s = oc[0][r]*oc[0][r] + oc[1][r]*oc[1][r]
                  + oc[2][r]*oc[2][r] + oc[3][r]*oc[3][r];
          s += __shfl_xor(s, 1); s += __shfl_xor(s, 2);
          s += __shfl_xor(s, 4); s += __shfl_xor(s, 8);
          rr[r] = rsqrtf(s*(1.f/64.f) + 1e-6f);
        }
#pragma unroll
        for (int n = 0; n < 4; ++n) {
          const float ow = onws[n*16 + lm];
#pragma unroll
          for (int r = 0; r < 4; ++r) val[n][r] = oc[n][r]*rr[r]*ow;
        }
      }
    }
    lds_barrier();

    // ---------------- finalize ----------------
    if (gA) {
#pragma unroll
      for (int n = 0; n < 4; ++n) {
        const int e = n*16 + lm;
        float s = colp[e*4+0] + colp[e*4+1] + colp[e*4+2] + colp[e*4+3];
        float rv = 1.f / fmaxf(sqrtf(s), 1e-12f);
#pragma unroll
        for (int r = 0; r < 4; ++r) Wreg[n][r] *= rv;
        uint2 u;
        u.x = cvtpk(Wreg[n][0], Wreg[n][1]);
        u.y = cvtpk(Wreg[n][2], Wreg[n][3]);
        *(uint2*)&WbT[e*ST2 + cb] = u;
      }
    }
    if (ch < NCH-1) PROMOTE();
    lds_barrier();
  }
  // last chunk's y
  STORE_Y((size_t)b*TT + (size_t)(NCH-1)*64);
#undef LOAD_PF
#undef PROMOTE
#undef STORE_Y
}

// ---------------------------------------------------------------------------
extern "C" void kernel_launch(void* const* d_in, const int* in_sizes, int n_in,
                              void* d_out, int out_size, void* d_ws, size_t ws_size,
                              hipStream_t stream)
{
  (void)in_sizes; (void)n_in; (void)out_size;
  const float* x    = (const float*)d_in[0];
  const float* cosb = (const float*)d_in[1];
  const float* sinb = (const float*)d_in[2];
  const float* Wq   = (const float*)d_in[3];
  const float* Wk   = (const float*)d_in[4];
  const float* Wv   = (const float*)d_in[5];
  const float* Wo   = (const float*)d_in[6];
  const float* lrw  = (const float*)d_in[7];
  const float* lrb  = (const float*)d_in[8];
  const float* onw  = (const float*)d_in[9];
  const float* wis  = (const float*)d_in[10];
  float* out = (float*)d_out;

  const size_t qN   = (size_t)BTOT*NH*DD;      // u16 (q, later y_hi)
  const size_t kN   = (size_t)BTOT*NKV*DD;     // u16
  const size_t wtN  = (size_t)2048*GK;         // u16 per plane
  const size_t wotN = (size_t)1024*GK;         // u16 per plane
  const size_t vN   = (size_t)BTOT*NKV*DD;     // f32
  const size_t etaN = (size_t)BTOT*NKV;        // f32
  const size_t need = (qN*2 + kN + wtN*2 + wotN*2)*2 + (vN + etaN)*4;
  if (ws_size < need) return;

  u16* qbuf  = (u16*)d_ws;          // q, then y_hi
  u16* ylo   = qbuf + qN;           // y_lo
  u16* kbuf  = ylo + qN;
  u16* wth   = kbuf + kN;
  u16* wtl   = wth + wtN;
  u16* woth  = wtl + wtN;
  u16* wotl  = woth + wotN;
  float* vbuf = (float*)(wotl + wotN);
  float* etab = vbuf + vN;

  wt_split<<<dim3(16,16), 256, 0, stream>>>(Wq, wth,           wtl,           NH*DD);
  wt_split<<<dim3( 8,16), 256, 0, stream>>>(Wk, wth + 1024*GK, wtl + 1024*GK, NKV*DD);
  wt_split<<<dim3( 8,16), 256, 0, stream>>>(Wv, wth + 1536*GK, wtl + 1536*GK, NKV*DD);
  wt_split<<<dim3(16,16), 256, 0, stream>>>(Wo, woth,          wotl,          NEMB);

  gemm_qkv<<<dim3(16,128), 256, 0, stream>>>(x, wth, wtl, qbuf, kbuf, vbuf, cosb, sinb);
  eta_kernel<<<BTOT/4, 256, 0, stream>>>(x, lrw, lrb, etab);

  const size_t SMEM = (size_t)(7*64*ST2)*2 + (size_t)(64*4 + 64)*4;  // 72960 B
  hipFuncSetAttribute(reinterpret_cast<const void*>(scan_mfma),
                      hipFuncAttributeMaxDynamicSharedMemorySize, (int)SMEM);
  scan_mfma<<<32, 512, SMEM, stream>>>(qbuf, qbuf, ylo, kbuf, vbuf, etab, onw, wis);

  gemm_out<<<dim3(8,128), 256, 0, stream>>>(qbuf, ylo, woth, wotl, out);
}

// Round 12
// 637.870 us; speedup vs baseline: 1.0698x; 1.0393x over previous
//
#include <hip/hip_runtime.h>
#include <math.h>

#define BB 4
#define TT 4096
#define NEMB 1024
#define NH 16
#define NKV 8
#define DD 64
#define NCH 64
#define BTOT (BB*TT)
#define KOFF 1024
#define VOFF 1536
#define GK 1024
#define ST2 80   // bf16 LDS row stride: 160B; balanced bank map

typedef __attribute__((ext_vector_type(8))) __bf16 bf16x8;
typedef __attribute__((ext_vector_type(4))) float f32x4;
typedef unsigned short u16;

__device__ inline u16 f2bf(float f){
  union { float f; unsigned u; } x; x.f = f;
  unsigned r = x.u + 0x7fffu + ((x.u >> 16) & 1u);
  return (u16)(r >> 16);
}
__device__ inline float bf2f(u16 u){
  union { unsigned u; float f; } x; x.u = ((unsigned)u) << 16; return x.f;
}
__device__ inline float asf(unsigned u){
  union { unsigned u; float f; } x; x.u = u; return x.f;
}
// HW RTNE pack: low16 = bf16(a), high16 = bf16(b)
__device__ inline unsigned cvtpk(float a, float b){
  unsigned r;
  asm("v_cvt_pk_bf16_f32 %0, %1, %2" : "=v"(r) : "v"(a), "v"(b));
  return r;
}
__device__ inline bf16x8 ldfrag(const u16* a, int outer, int k0, int lm, int lh){
  return *(const bf16x8*)(a + (size_t)(outer + lm)*ST2 + k0 + 8*lh);
}
// Barrier draining only LDS (lgkmcnt), not global traffic.
__device__ inline void lds_barrier(){
  __builtin_amdgcn_sched_barrier(0);
  asm volatile("s_waitcnt lgkmcnt(0)" ::: "memory");
  __builtin_amdgcn_s_barrier();
  __builtin_amdgcn_sched_barrier(0);
}

// ---------------------------------------------------------------------------
// Merged weight transpose + hi/lo split: one launch for [Wq|Wk|Wv] and Wo.
// grid.x = 48 column-blocks (0..31 -> qkv planes, 32..47 -> wo planes)
// ---------------------------------------------------------------------------
__global__ void __launch_bounds__(256)
wt_split_all(const float* __restrict__ Wq, const float* __restrict__ Wk,
             const float* __restrict__ Wv, const float* __restrict__ Wo,
             u16* __restrict__ wth, u16* __restrict__ wtl,
             u16* __restrict__ woth, u16* __restrict__ wotl)
{
  __shared__ float ts[64][68];
  const int tid = threadIdx.x;
  const int n0 = blockIdx.x*64, k0 = blockIdx.y*64;
  const int tx = tid & 15, ty = tid >> 4;

  const float* src; int N, ncol, dstcol; u16 *dh, *dl;
  if (n0 < 1024)      { src = Wq; N = 1024; ncol = n0;        dstcol = n0;        dh = wth;  dl = wtl;  }
  else if (n0 < 1536) { src = Wk; N = 512;  ncol = n0 - 1024; dstcol = n0;        dh = wth;  dl = wtl;  }
  else if (n0 < 2048) { src = Wv; N = 512;  ncol = n0 - 1536; dstcol = n0;        dh = wth;  dl = wtl;  }
  else                { src = Wo; N = 1024; ncol = n0 - 2048; dstcol = n0 - 2048; dh = woth; dl = wotl; }

#pragma unroll
  for (int i = 0; i < 4; ++i) {
    int k = ty + i*16;
    float4 v = *(const float4*)(src + (size_t)(k0+k)*N + ncol + tx*4);
    ts[k][tx*4+0]=v.x; ts[k][tx*4+1]=v.y; ts[k][tx*4+2]=v.z; ts[k][tx*4+3]=v.w;
  }
  __syncthreads();
#pragma unroll
  for (int i = 0; i < 4; ++i) {
    int n = ty + i*16;
    ushort4 uh, ul;
    float f0 = ts[tx*4+0][n], f1 = ts[tx*4+1][n];
    float f2 = ts[tx*4+2][n], f3 = ts[tx*4+3][n];
    uh.x = f2bf(f0); ul.x = f2bf(f0 - bf2f(uh.x));
    uh.y = f2bf(f1); ul.y = f2bf(f1 - bf2f(uh.y));
    uh.z = f2bf(f2); ul.z = f2bf(f2 - bf2f(uh.z));
    uh.w = f2bf(f3); ul.w = f2bf(f3 - bf2f(uh.w));
    *(ushort4*)(dh + (size_t)(dstcol+n)*GK + k0 + tx*4) = uh;
    *(ushort4*)(dl + (size_t)(dstcol+n)*GK + k0 + tx*4) = ul;
  }
}

// ---------------------------------------------------------------------------
// QKV GEMM (unchanged from R8-R11)
// ---------------------------------------------------------------------------
__global__ void __launch_bounds__(256)
gemm_qkv(const float* __restrict__ x,
         const u16* __restrict__ Bth, const u16* __restrict__ Btl,
         u16* __restrict__ qb, u16* __restrict__ kb, float* __restrict__ vb,
         const float* __restrict__ cosb, const float* __restrict__ sinb)
{
  __shared__ u16 AsH[128*64];
  __shared__ u16 AsL[128*64];
  __shared__ u16 BsH[128*64];
  __shared__ u16 BsL[128*64];

  const int tid = threadIdx.x;
  const int w = tid >> 6, l = tid & 63, lm = l & 15, lh = l >> 4;
  const int bm = blockIdx.y << 7, bn = blockIdx.x << 7;
  const int wr = w >> 1, wc = w & 1;

  f32x4 acc[4][4];
#pragma unroll
  for (int i = 0; i < 4; ++i)
#pragma unroll
    for (int j = 0; j < 4; ++j) { f32x4 z = {0.f,0.f,0.f,0.f}; acc[i][j] = z; }

  const int lr8 = l >> 3, sp = l & 7;
  const int ar = tid >> 3, as_ = tid & 7;

  for (int kt = 0; kt < GK; kt += 64) {
    __syncthreads();
#pragma unroll
    for (int c = 0; c < 4; ++c) {
      const int r = (w*4 + c)*8 + lr8;
      const int s = sp ^ (r & 7);
      const u16* gh = Bth + (size_t)(bn + r)*GK + kt + s*8;
      const u16* gl = Btl + (size_t)(bn + r)*GK + kt + s*8;
      __builtin_amdgcn_global_load_lds(
        (const __attribute__((address_space(1))) void*)gh,
        (__attribute__((address_space(3))) void*)(BsH + (w*4 + c)*512), 16, 0, 0);
      __builtin_amdgcn_global_load_lds(
        (const __attribute__((address_space(1))) void*)gl,
        (__attribute__((address_space(3))) void*)(BsL + (w*4 + c)*512), 16, 0, 0);
    }
#pragma unroll
    for (int p = 0; p < 4; ++p) {
      const int r = p*32 + ar;
      const float* gx = x + (size_t)(bm + r)*NEMB + kt + as_*8;
      float4 f0 = *(const float4*)gx;
      float4 f1 = *(const float4*)(gx + 4);
      float fv[8] = {f0.x,f0.y,f0.z,f0.w,f1.x,f1.y,f1.z,f1.w};
      uint4 hq, lq;
      hq.x = cvtpk(fv[0], fv[1]); hq.y = cvtpk(fv[2], fv[3]);
      hq.z = cvtpk(fv[4], fv[5]); hq.w = cvtpk(fv[6], fv[7]);
      float l0 = fv[0] - asf(hq.x << 16), l1 = fv[1] - asf(hq.x & 0xffff0000u);
      float l2 = fv[2] - asf(hq.y << 16), l3 = fv[3] - asf(hq.y & 0xffff0000u);
      float l4 = fv[4] - asf(hq.z << 16), l5 = fv[5] - asf(hq.z & 0xffff0000u);
      float l6 = fv[6] - asf(hq.w << 16), l7 = fv[7] - asf(hq.w & 0xffff0000u);
      lq.x = cvtpk(l0, l1); lq.y = cvtpk(l2, l3);
      lq.z = cvtpk(l4, l5); lq.w = cvtpk(l6, l7);
      const int off = r*64 + (as_ ^ (r & 7))*8;
      *(uint4*)&AsH[off] = hq;
      *(uint4*)&AsL[off] = lq;
    }
    __syncthreads();
#pragma unroll
    for (int kk = 0; kk < 2; ++kk) {
      bf16x8 ah[4], al[4], bh[4], bl[4];
#pragma unroll
      for (int mi = 0; mi < 4; ++mi) {
        int r = wr*64 + mi*16 + lm;
        int s = (kk*4 + lh) ^ (r & 7);
        ah[mi] = *(const bf16x8*)(AsH + r*64 + s*8);
        al[mi] = *(const bf16x8*)(AsL + r*64 + s*8);
      }
#pragma unroll
      for (int nj = 0; nj < 4; ++nj) {
        int r = wc*64 + nj*16 + lm;
        int s = (kk*4 + lh) ^ (r & 7);
        bh[nj] = *(const bf16x8*)(BsH + r*64 + s*8);
        bl[nj] = *(const bf16x8*)(BsL + r*64 + s*8);
      }
#pragma unroll
      for (int mi = 0; mi < 4; ++mi)
#pragma unroll
        for (int nj = 0; nj < 4; ++nj) {
          acc[mi][nj] = __builtin_amdgcn_mfma_f32_16x16x32_bf16(ah[mi], bh[nj], acc[mi][nj], 0,0,0);
          acc[mi][nj] = __builtin_amdgcn_mfma_f32_16x16x32_bf16(al[mi], bh[nj], acc[mi][nj], 0,0,0);
          acc[mi][nj] = __builtin_amdgcn_mfma_f32_16x16x32_bf16(ah[mi], bl[nj], acc[mi][nj], 0,0,0);
        }
    }
  }

  const int colbase = bn + wc*64;
  if (colbase < VOFF) {
    u16* C; int ldcc, cb2;
    if (colbase < KOFF) { C = qb; ldcc = NH*DD;  cb2 = colbase; }
    else                { C = kb; ldcc = NKV*DD; cb2 = colbase - KOFF; }
#pragma unroll
    for (int mi = 0; mi < 4; ++mi) {
#pragma unroll
      for (int r = 0; r < 4; ++r) {
        const int rl = wr*64 + mi*16 + 4*lh + r;
        const int t = (bm + rl) & (TT - 1);
        const float c0 = cosb[t*32 + lm],      s0 = sinb[t*32 + lm];
        const float c1 = cosb[t*32 + 16 + lm], s1 = sinb[t*32 + 16 + lm];
        float o0 = acc[mi][0][r]*c0 - acc[mi][2][r]*s0;
        float o1 = acc[mi][1][r]*c1 - acc[mi][3][r]*s1;
        float o2 = acc[mi][2][r]*c0 + acc[mi][0][r]*s0;
        float o3 = acc[mi][3][r]*c1 + acc[mi][1][r]*s1;
        float ss = o0*o0 + o1*o1 + o2*o2 + o3*o3;
        ss += __shfl_xor(ss, 1); ss += __shfl_xor(ss, 2);
        ss += __shfl_xor(ss, 4); ss += __shfl_xor(ss, 8);
        const float rr = rsqrtf(ss*(1.f/64.f) + 1e-6f);
        u16* dst = C + (size_t)(bm + rl)*ldcc + cb2 + lm;
        dst[0]  = f2bf(o0*rr);
        dst[16] = f2bf(o1*rr);
        dst[32] = f2bf(o2*rr);
        dst[48] = f2bf(o3*rr);
      }
    }
  } else {
    const int cb2 = colbase - VOFF;
#pragma unroll
    for (int mi = 0; mi < 4; ++mi)
#pragma unroll
      for (int nj = 0; nj < 4; ++nj)
#pragma unroll
        for (int r = 0; r < 4; ++r) {
          const int rl = wr*64 + mi*16 + 4*lh + r;
          vb[(size_t)(bm + rl)*(NKV*DD) + cb2 + nj*16 + lm] = acc[mi][nj][r];
        }
  }
}

// ---------------------------------------------------------------------------
// Out GEMM (unchanged, proven R5)
// ---------------------------------------------------------------------------
__global__ void __launch_bounds__(256)
gemm_out(const u16* __restrict__ Ah, const u16* __restrict__ Al,
         const u16* __restrict__ Bth, const u16* __restrict__ Btl,
         float* __restrict__ C)
{
  __shared__ u16 AsH[128*64];
  __shared__ u16 AsL[128*64];
  __shared__ u16 BsH[128*64];
  __shared__ u16 BsL[128*64];
  const int tid = threadIdx.x;
  const int w = tid >> 6, l = tid & 63, lm = l & 15, lh = l >> 4;
  const int bm = blockIdx.y << 7, bn = blockIdx.x << 7;
  const int wr = w >> 1, wc = w & 1;

  f32x4 acc[4][4];
#pragma unroll
  for (int i = 0; i < 4; ++i)
#pragma unroll
    for (int j = 0; j < 4; ++j) { f32x4 z = {0.f,0.f,0.f,0.f}; acc[i][j] = z; }

  const int lr8 = l >> 3, sp = l & 7;
  for (int kt = 0; kt < GK; kt += 64) {
    __syncthreads();
#pragma unroll
    for (int c = 0; c < 4; ++c) {
      const int r = (w*4 + c)*8 + lr8;
      const int s = sp ^ (r & 7);
      const u16* gah = Ah  + (size_t)(bm + r)*(NH*DD) + kt + s*8;
      const u16* gal = Al  + (size_t)(bm + r)*(NH*DD) + kt + s*8;
      const u16* gbh = Bth + (size_t)(bn + r)*GK      + kt + s*8;
      const u16* gbl = Btl + (size_t)(bn + r)*GK      + kt + s*8;
      __builtin_amdgcn_global_load_lds(
        (const __attribute__((address_space(1))) void*)gah,
        (__attribute__((address_space(3))) void*)(AsH + (w*4 + c)*512), 16, 0, 0);
      __builtin_amdgcn_global_load_lds(
        (const __attribute__((address_space(1))) void*)gal,
        (__attribute__((address_space(3))) void*)(AsL + (w*4 + c)*512), 16, 0, 0);
      __builtin_amdgcn_global_load_lds(
        (const __attribute__((address_space(1))) void*)gbh,
        (__attribute__((address_space(3))) void*)(BsH + (w*4 + c)*512), 16, 0, 0);
      __builtin_amdgcn_global_load_lds(
        (const __attribute__((address_space(1))) void*)gbl,
        (__attribute__((address_space(3))) void*)(BsL + (w*4 + c)*512), 16, 0, 0);
    }
    __syncthreads();
#pragma unroll
    for (int kk = 0; kk < 2; ++kk) {
      bf16x8 ah[4], al[4], bh[4], bl[4];
#pragma unroll
      for (int mi = 0; mi < 4; ++mi) {
        int r = wr*64 + mi*16 + lm;
        int s = (kk*4 + lh) ^ (r & 7);
        ah[mi] = *(const bf16x8*)(AsH + r*64 + s*8);
        al[mi] = *(const bf16x8*)(AsL + r*64 + s*8);
      }
#pragma unroll
      for (int nj = 0; nj < 4; ++nj) {
        int r = wc*64 + nj*16 + lm;
        int s = (kk*4 + lh) ^ (r & 7);
        bh[nj] = *(const bf16x8*)(BsH + r*64 + s*8);
        bl[nj] = *(const bf16x8*)(BsL + r*64 + s*8);
      }
#pragma unroll
      for (int mi = 0; mi < 4; ++mi)
#pragma unroll
        for (int nj = 0; nj < 4; ++nj) {
          acc[mi][nj] = __builtin_amdgcn_mfma_f32_16x16x32_bf16(ah[mi], bh[nj], acc[mi][nj], 0,0,0);
          acc[mi][nj] = __builtin_amdgcn_mfma_f32_16x16x32_bf16(al[mi], bh[nj], acc[mi][nj], 0,0,0);
          acc[mi][nj] = __builtin_amdgcn_mfma_f32_16x16x32_bf16(ah[mi], bl[nj], acc[mi][nj], 0,0,0);
        }
    }
  }
#pragma unroll
  for (int mi = 0; mi < 4; ++mi)
#pragma unroll
    for (int nj = 0; nj < 4; ++nj)
#pragma unroll
      for (int r = 0; r < 4; ++r) {
        const int rl = wr*64 + mi*16 + 4*lh + r;
        C[(size_t)(bm + rl)*NEMB + bn + wc*64 + nj*16 + lm] = acc[mi][nj][r];
      }
}

// ---------------------------------------------------------------------------
// eta = softplus(x @ lr_w + lr_b)  (unchanged)
// ---------------------------------------------------------------------------
__global__ void __launch_bounds__(256)
eta_kernel(const float* __restrict__ x, const float* __restrict__ lr_w,
           const float* __restrict__ lr_b, float* __restrict__ etab)
{
  __shared__ float lw[NKV*NEMB];
  const int tid = threadIdx.x;
  for (int idx = tid; idx < NEMB*NKV; idx += 256) {
    int i = idx >> 3, k2 = idx & 7;
    lw[k2*NEMB + i] = lr_w[idx];
  }
  __syncthreads();
  const int w = tid >> 6, lane = tid & 63;
  const size_t tok = (size_t)blockIdx.x*4 + w;
  const float* xr = x + tok*NEMB;
  float acc[8] = {0.f,0.f,0.f,0.f,0.f,0.f,0.f,0.f};
  for (int j = 0; j < 16; ++j) {
    float xv = xr[lane + 64*j];
#pragma unroll
    for (int k2 = 0; k2 < 8; ++k2)
      acc[k2] += xv * lw[k2*NEMB + lane + 64*j];
  }
#pragma unroll
  for (int k2 = 0; k2 < 8; ++k2)
#pragma unroll
    for (int off = 32; off; off >>= 1) acc[k2] += __shfl_xor(acc[k2], off);
  if (lane == 0) {
#pragma unroll
    for (int k2 = 0; k2 < 8; ++k2) {
      float z = acc[k2] + lr_b[k2];
      etab[tok*NKV + k2] = (z > 20.f) ? z : log1pf(expf(z));
    }
  }
}

// ---------------------------------------------------------------------------
// MFMA TTT scan, R12 = R11 minus ALL s_setprio (suspected lockstep-phase
// priority inversion, the only un-isolated R7->R8 regression candidate).
// Numerics identical to R11 (0.082).
// ---------------------------------------------------------------------------
__global__ void __launch_bounds__(512, 2)
scan_mfma(const u16* __restrict__ qsrc, u16* __restrict__ yhi,
          u16* __restrict__ ylo,
          const u16* __restrict__ kbuf,
          const float* __restrict__ vbuf, const float* __restrict__ etabuf,
          const float* __restrict__ onw, const float* __restrict__ wis_p)
{
  extern __shared__ char smraw[];
  u16* KbT = (u16*)smraw;             // [64][ST2] K^T[d][c]
  u16* Qb0 = KbT + 64*ST2;            // [64][ST2] Q_h0[c][d]
  u16* Qb1 = Qb0 + 64*ST2;            // [64][ST2] Q_h1[c][d]
  u16* Ab0 = Qb1 + 64*ST2;            // [64][ST2] A_h0[ci][cj]
  u16* Ab1 = Ab0 + 64*ST2;            // [64][ST2] A_h1[ci][cj]
  u16* EsT = Ab1 + 64*ST2;            // [64][ST2] negEs^T[e][c]
  u16* WbT = EsT + 64*ST2;            // [64][ST2] W^T[e][d] bf16
  float* colp = (float*)(WbT + 64*ST2); // [64][4]
  float* onws = colp + 64*4;          // [64]

  const int tid = threadIdx.x;
  const int b = blockIdx.x >> 3, kh = blockIdx.x & 7;
  const int w = tid >> 6, l = tid & 63, lm = l & 15, lh = l >> 4;
  const bool gA = (w < 4);
  const int m0 = (w & 3) * 16;
  const int cb = m0 + lh*4;
  const float wis = *wis_p;

  float Wreg[4][4];   // A-group only
  if (gA) {
#pragma unroll
    for (int n = 0; n < 4; ++n) {
      const int e = n*16 + lm;
#pragma unroll
      for (int r = 0; r < 4; ++r)
        Wreg[n][r] = ((cb + r) == e) ? wis : 0.f;
      uint2 u;
      u.x = cvtpk(Wreg[n][0], Wreg[n][1]);
      u.y = cvtpk(Wreg[n][2], Wreg[n][3]);
      *(uint2*)&WbT[e*ST2 + cb] = u;
    }
  }
  if (tid < 64) onws[tid] = onw[tid];

  const int st = tid & 255;           // staging index within group B
  const int stc4 = (st >> 4)*4;
  const int std4 = (st & 15)*4;

  ushort4 kpre[4], qpre0[4], qpre1[4];   // group B staging regs
  bf16x8 akp0, akp1, ak0, ak1;           // all waves
  float vpre[4][4], vcur[4][4];          // group A
  float epre[4], ecur[4];                // group A
  float val[4][4];                       // deferred y (both groups)

#define LOAD_PF(CH)                                                            \
  { const size_t rb = (size_t)b*TT + (size_t)(CH)*64;                          \
    if (!gA) {                                                                 \
      _Pragma("unroll")                                                        \
      for (int i = 0; i < 4; ++i) {                                            \
        kpre[i]  = *(const ushort4*)(kbuf + (rb+stc4+i)*(NKV*DD) + kh*DD + std4);\
        qpre0[i] = *(const ushort4*)(qsrc + (rb+stc4+i)*(NH*DD) + (kh*2)*DD + std4);\
        qpre1[i] = *(const ushort4*)(qsrc + (rb+stc4+i)*(NH*DD) + (kh*2+1)*DD + std4);\
      }                                                                        \
    }                                                                          \
    akp0 = *(const bf16x8*)(kbuf + (rb+m0+lm)*(NKV*DD) + kh*DD + 8*lh);        \
    akp1 = *(const bf16x8*)(kbuf + (rb+m0+lm)*(NKV*DD) + kh*DD + 32 + 8*lh);   \
    if (gA) {                                                                  \
      _Pragma("unroll")                                                        \
      for (int n = 0; n < 4; ++n)                                              \
        _Pragma("unroll")                                                      \
        for (int r = 0; r < 4; ++r)                                            \
          vpre[n][r] = vbuf[(rb+cb+r)*(NKV*DD) + kh*DD + n*16 + lm];           \
      _Pragma("unroll")                                                        \
      for (int r = 0; r < 4; ++r) epre[r] = etabuf[(rb+cb+r)*NKV + kh];        \
    } }

#define PROMOTE()                                                              \
  { ak0 = akp0; ak1 = akp1;                                                    \
    if (gA) {                                                                  \
      _Pragma("unroll")                                                        \
      for (int n = 0; n < 4; ++n)                                              \
        _Pragma("unroll")                                                      \
        for (int r = 0; r < 4; ++r) vcur[n][r] = vpre[n][r];                   \
      _Pragma("unroll")                                                        \
      for (int r = 0; r < 4; ++r) ecur[r] = epre[r];                           \
    } else {                                                                   \
      ushort4 u;                                                               \
      u.x=kpre[0].x; u.y=kpre[1].x; u.z=kpre[2].x; u.w=kpre[3].x;              \
      *(ushort4*)&KbT[(std4+0)*ST2 + stc4] = u;                                \
      u.x=kpre[0].y; u.y=kpre[1].y; u.z=kpre[2].y; u.w=kpre[3].y;              \
      *(ushort4*)&KbT[(std4+1)*ST2 + stc4] = u;                                \
      u.x=kpre[0].z; u.y=kpre[1].z; u.z=kpre[2].z; u.w=kpre[3].z;              \
      *(ushort4*)&KbT[(std4+2)*ST2 + stc4] = u;                                \
      u.x=kpre[0].w; u.y=kpre[1].w; u.z=kpre[2].w; u.w=kpre[3].w;              \
      *(ushort4*)&KbT[(std4+3)*ST2 + stc4] = u;                                \
      _Pragma("unroll")                                                        \
      for (int i = 0; i < 4; ++i) {                                            \
        *(ushort4*)&Qb0[(stc4+i)*ST2 + std4] = qpre0[i];                       \
        *(ushort4*)&Qb1[(stc4+i)*ST2 + std4] = qpre1[i];                       \
      }                                                                        \
    } }

#define STORE_Y(RB)                                                            \
  { const int ho = (kh*2 + (gA ? 0 : 1))*DD;                                   \
    _Pragma("unroll")                                                          \
    for (int n = 0; n < 4; ++n) {                                              \
      const int e = n*16 + lm;                                                 \
      unsigned h01 = cvtpk(val[n][0], val[n][1]);                              \
      unsigned h23 = cvtpk(val[n][2], val[n][3]);                              \
      float l0 = val[n][0] - asf(h01 << 16);                                   \
      float l1 = val[n][1] - asf(h01 & 0xffff0000u);                           \
      float l2 = val[n][2] - asf(h23 << 16);                                   \
      float l3 = val[n][3] - asf(h23 & 0xffff0000u);                           \
      unsigned q01 = cvtpk(l0, l1), q23 = cvtpk(l2, l3);                       \
      const size_t i0 = ((RB) + cb)*(size_t)(NH*DD) + ho + e;                  \
      yhi[i0]           = (u16)h01;                                            \
      yhi[i0 + NH*DD]   = (u16)(h01 >> 16);                                    \
      yhi[i0 + 2*NH*DD] = (u16)h23;                                            \
      yhi[i0 + 3*NH*DD] = (u16)(h23 >> 16);                                    \
      ylo[i0]            = (u16)q01;                                           \
      ylo[i0 + NH*DD]    = (u16)(q01 >> 16);                                   \
      ylo[i0 + 2*NH*DD]  = (u16)q23;                                           \
      ylo[i0 + 3*NH*DD]  = (u16)(q23 >> 16);                                   \
    } }

  LOAD_PF(0);
  PROMOTE();
  lds_barrier();

  f32x4 oc[4];
  bf16x8 wfr[8];

  for (int ch = 0; ch < NCH; ++ch) {
    const size_t rowbase = (size_t)b*TT + (size_t)ch*64;

    if (ch < NCH-1) LOAD_PF(ch+1);
    if (ch > 0) STORE_Y(rowbase - 64);   // prev chunk's y; never blocks

    // ---------------- phase1 ----------------
    if (gA) {
      // E = K·W -> Es; then Q0·W partial for out_h0
      f32x4 eac[4];
#pragma unroll
      for (int n = 0; n < 4; ++n) { f32x4 z = {0.f,0.f,0.f,0.f}; eac[n] = z; }
#pragma unroll
      for (int n = 0; n < 4; ++n) {
        wfr[2*n]   = ldfrag(WbT, n*16,  0, lm, lh);
        wfr[2*n+1] = ldfrag(WbT, n*16, 32, lm, lh);
        eac[n] = __builtin_amdgcn_mfma_f32_16x16x32_bf16(ak0, wfr[2*n],   eac[n], 0,0,0);
        eac[n] = __builtin_amdgcn_mfma_f32_16x16x32_bf16(ak1, wfr[2*n+1], eac[n], 0,0,0);
      }
#pragma unroll
      for (int n = 0; n < 4; ++n) {
        const int e = n*16 + lm;
        uint2 u;
        u.x = cvtpk(ecur[0]*(vcur[n][0] - eac[n][0]),
                    ecur[1]*(vcur[n][1] - eac[n][1]));
        u.y = cvtpk(ecur[2]*(vcur[n][2] - eac[n][2]),
                    ecur[3]*(vcur[n][3] - eac[n][3]));
        *(uint2*)&EsT[e*ST2 + cb] = u;
      }
      bf16x8 aQ0 = ldfrag(Qb0, m0, 0, lm, lh), aQ1 = ldfrag(Qb0, m0, 32, lm, lh);
#pragma unroll
      for (int n = 0; n < 4; ++n) {
        f32x4 z = {0.f,0.f,0.f,0.f};
        z = __builtin_amdgcn_mfma_f32_16x16x32_bf16(aQ0, wfr[2*n],   z, 0,0,0);
        z = __builtin_amdgcn_mfma_f32_16x16x32_bf16(aQ1, wfr[2*n+1], z, 0,0,0);
        oc[n] = z;
      }
    } else {
      // AT = K·Q^T both heads; mask tril -> Ab0/Ab1; prefetch wfr for phase2
      f32x4 a0c[4], a1c[4];
#pragma unroll
      for (int n = 0; n < 4; ++n) { f32x4 z = {0.f,0.f,0.f,0.f}; a0c[n] = z; a1c[n] = z; }
#pragma unroll
      for (int n = 0; n < 4; ++n) {
        a0c[n] = __builtin_amdgcn_mfma_f32_16x16x32_bf16(ak0, ldfrag(Qb0, n*16,  0, lm, lh), a0c[n], 0,0,0);
        a0c[n] = __builtin_amdgcn_mfma_f32_16x16x32_bf16(ak1, ldfrag(Qb0, n*16, 32, lm, lh), a0c[n], 0,0,0);
        a1c[n] = __builtin_amdgcn_mfma_f32_16x16x32_bf16(ak0, ldfrag(Qb1, n*16,  0, lm, lh), a1c[n], 0,0,0);
        a1c[n] = __builtin_amdgcn_mfma_f32_16x16x32_bf16(ak1, ldfrag(Qb1, n*16, 32, lm, lh), a1c[n], 0,0,0);
      }
#pragma unroll
      for (int n = 0; n < 4; ++n) {
        const int ci = n*16 + lm;
        uint2 u0, u1;
        u0.x = cvtpk((cb+0 <= ci) ? a0c[n][0] : 0.f, (cb+1 <= ci) ? a0c[n][1] : 0.f);
        u0.y = cvtpk((cb+2 <= ci) ? a0c[n][2] : 0.f, (cb+3 <= ci) ? a0c[n][3] : 0.f);
        u1.x = cvtpk((cb+0 <= ci) ? a1c[n][0] : 0.f, (cb+1 <= ci) ? a1c[n][1] : 0.f);
        u1.y = cvtpk((cb+2 <= ci) ? a1c[n][2] : 0.f, (cb+3 <= ci) ? a1c[n][3] : 0.f);
        *(uint2*)&Ab0[ci*ST2 + cb] = u0;
        *(uint2*)&Ab1[ci*ST2 + cb] = u1;
      }
#pragma unroll
      for (int n = 0; n < 4; ++n) {
        wfr[2*n]   = ldfrag(WbT, n*16,  0, lm, lh);
        wfr[2*n+1] = ldfrag(WbT, n*16, 32, lm, lh);
      }
    }
    lds_barrier();

    // ---------------- phase2 ----------------
    {
      bf16x8 esf[8];
#pragma unroll
      for (int n = 0; n < 4; ++n) {
        esf[2*n]   = ldfrag(EsT, n*16,  0, lm, lh);
        esf[2*n+1] = ldfrag(EsT, n*16, 32, lm, lh);
      }
      if (gA) {
        bf16x8 aA0 = ldfrag(Ab0, m0, 0, lm, lh), aA1 = ldfrag(Ab0, m0, 32, lm, lh);
#pragma unroll
        for (int n = 0; n < 4; ++n) {
          oc[n] = __builtin_amdgcn_mfma_f32_16x16x32_bf16(aA0, esf[2*n],   oc[n], 0,0,0);
          oc[n] = __builtin_amdgcn_mfma_f32_16x16x32_bf16(aA1, esf[2*n+1], oc[n], 0,0,0);
        }
        float rr[4];
#pragma unroll
        for (int r = 0; r < 4; ++r) {
          float s = oc[0][r]*oc[0][r] + oc[1][r]*oc[1][r]
                  + oc[2][r]*oc[2][r] + oc[3][r]*oc[3][r];
          s += __shfl_xor(s, 1); s += __shfl_xor(s, 2);
          s += __shfl_xor(s, 4); s += __shfl_xor(s, 8);
          rr[r] = rsqrtf(s*(1.f/64.f) + 1e-6f);
        }
#pragma unroll
        for (int n = 0; n < 4; ++n) {
          const float ow = onws[n*16 + lm];
#pragma unroll
          for (int r = 0; r < 4; ++r) val[n][r] = oc[n][r]*rr[r]*ow;
        }
        // U' = K^T·negEs; W += U'/64; colnorm partials
        bf16x8 aT0 = ldfrag(KbT, m0, 0, lm, lh), aT1 = ldfrag(KbT, m0, 32, lm, lh);
#pragma unroll
        for (int n = 0; n < 4; ++n) {
          f32x4 z = {0.f,0.f,0.f,0.f};
          z = __builtin_amdgcn_mfma_f32_16x16x32_bf16(aT0, esf[2*n],   z, 0,0,0);
          z = __builtin_amdgcn_mfma_f32_16x16x32_bf16(aT1, esf[2*n+1], z, 0,0,0);
          float p = 0.f;
#pragma unroll
          for (int r = 0; r < 4; ++r) {
            Wreg[n][r] += z[r]*(1.f/64.f);
            p += Wreg[n][r]*Wreg[n][r];
          }
          p += __shfl_xor(p, 16);
          p += __shfl_xor(p, 32);
          if (lh == 0) colp[(n*16 + lm)*4 + (w & 3)] = p;
        }
      } else {
        bf16x8 aQ0 = ldfrag(Qb1, m0, 0, lm, lh), aQ1 = ldfrag(Qb1, m0, 32, lm, lh);
        bf16x8 aA0 = ldfrag(Ab1, m0, 0, lm, lh), aA1 = ldfrag(Ab1, m0, 32, lm, lh);
#pragma unroll
        for (int n = 0; n < 4; ++n) {
          f32x4 z = {0.f,0.f,0.f,0.f};
          z = __builtin_amdgcn_mfma_f32_16x16x32_bf16(aQ0, wfr[2*n],   z, 0,0,0);
          z = __builtin_amdgcn_mfma_f32_16x16x32_bf16(aQ1, wfr[2*n+1], z, 0,0,0);
          z = __builtin_amdgcn_mfma_f32_16x16x32_bf16(aA0, esf[2*n],   z, 0,0,0);
          z = __builtin_amdgcn_mfma_f32_16x16x32_bf16(aA1, esf[2*n+1], z, 0,0,0);
          oc[n] = z;
        }
        float rr[4];
#pragma unroll
        for (int r = 0; r < 4; ++r) {
          float s = oc[0][r]*oc[0][r] + oc[1][r]*oc[1][r]
                  + oc[2][r]*oc[2][r] + oc[3][r]*oc[3][r];
          s += __shfl_xor(s, 1); s += __shfl_xor(s, 2);
          s += __shfl_xor(s, 4); s += __shfl_xor(s, 8);
          rr[r] = rsqrtf(s*(1.f/64.f) + 1e-6f);
        }
#pragma unroll
        for (int n = 0; n < 4; ++n) {
          const float ow = onws[n*16 + lm];
#pragma unroll
          for (int r = 0; r < 4; ++r) val[n][r] = oc[n][r]*rr[r]*ow;
        }
      }
    }
    lds_barrier();

    // ---------------- finalize ----------------
    if (gA) {
#pragma unroll
      for (int n = 0; n < 4; ++n) {
        const int e = n*16 + lm;
        float s = colp[e*4+0] + colp[e*4+1] + colp[e*4+2] + colp[e*4+3];
        float rv = 1.f / fmaxf(sqrtf(s), 1e-12f);
#pragma unroll
        for (int r = 0; r < 4; ++r) Wreg[n][r] *= rv;
        uint2 u;
        u.x = cvtpk(Wreg[n][0], Wreg[n][1]);
        u.y = cvtpk(Wreg[n][2], Wreg[n][3]);
        *(uint2*)&WbT[e*ST2 + cb] = u;
      }
    }
    if (ch < NCH-1) PROMOTE();
    lds_barrier();
  }
  // last chunk's y
  STORE_Y((size_t)b*TT + (size_t)(NCH-1)*64);
#undef LOAD_PF
#undef PROMOTE
#undef STORE_Y
}

// ---------------------------------------------------------------------------
extern "C" void kernel_launch(void* const* d_in, const int* in_sizes, int n_in,
                              void* d_out, int out_size, void* d_ws, size_t ws_size,
                              hipStream_t stream)
{
  (void)in_sizes; (void)n_in; (void)out_size;
  const float* x    = (const float*)d_in[0];
  const float* cosb = (const float*)d_in[1];
  const float* sinb = (const float*)d_in[2];
  const float* Wq   = (const float*)d_in[3];
  const float* Wk   = (const float*)d_in[4];
  const float* Wv   = (const float*)d_in[5];
  const float* Wo   = (const float*)d_in[6];
  const float* lrw  = (const float*)d_in[7];
  const float* lrb  = (const float*)d_in[8];
  const float* onw  = (const float*)d_in[9];
  const float* wis  = (const float*)d_in[10];
  float* out = (float*)d_out;

  const size_t qN   = (size_t)BTOT*NH*DD;      // u16 (q, later y_hi)
  const size_t kN   = (size_t)BTOT*NKV*DD;     // u16
  const size_t wtN  = (size_t)2048*GK;         // u16 per plane
  const size_t wotN = (size_t)1024*GK;         // u16 per plane
  const size_t vN   = (size_t)BTOT*NKV*DD;     // f32
  const size_t etaN = (size_t)BTOT*NKV;        // f32
  const size_t need = (qN*2 + kN + wtN*2 + wotN*2)*2 + (vN + etaN)*4;
  if (ws_size < need) return;

  u16* qbuf  = (u16*)d_ws;          // q, then y_hi
  u16* ylo   = qbuf + qN;           // y_lo
  u16* kbuf  = ylo + qN;
  u16* wth   = kbuf + kN;
  u16* wtl   = wth + wtN;
  u16* woth  = wtl + wtN;
  u16* wotl  = woth + wotN;
  float* vbuf = (float*)(wotl + wotN);
  float* etab = vbuf + vN;

  wt_split_all<<<dim3(48,16), 256, 0, stream>>>(Wq, Wk, Wv, Wo,
                                                wth, wtl, woth, wotl);

  gemm_qkv<<<dim3(16,128), 256, 0, stream>>>(x, wth, wtl, qbuf, kbuf, vbuf, cosb, sinb);
  eta_kernel<<<BTOT/4, 256, 0, stream>>>(x, lrw, lrb, etab);

  const size_t SMEM = (size_t)(7*64*ST2)*2 + (size_t)(64*4 + 64)*4;  // 72960 B
  hipFuncSetAttribute(reinterpret_cast<const void*>(scan_mfma),
                      hipFuncAttributeMaxDynamicSharedMemorySize, (int)SMEM);
  scan_mfma<<<32, 512, SMEM, stream>>>(qbuf, qbuf, ylo, kbuf, vbuf, etab, onw, wis);

  gemm_out<<<dim3(8,128), 256, 0, stream>>>(qbuf, ylo, woth, wotl, out);
}

// Round 14
// 582.941 us; speedup vs baseline: 1.1706x; 1.0942x over previous
//
#include <hip/hip_runtime.h>
#include <math.h>

#define BB 4
#define TT 4096
#define NEMB 1024
#define NH 16
#define NKV 8
#define DD 64
#define NCH 64
#define BTOT (BB*TT)
#define KOFF 1024
#define VOFF 1536
#define GK 1024
#define ST2 80   // bf16 LDS row stride: 160B; balanced bank map

typedef __attribute__((ext_vector_type(8))) __bf16 bf16x8;
typedef __attribute__((ext_vector_type(4))) float f32x4;
typedef unsigned short u16;

__device__ inline u16 f2bf(float f){
  union { float f; unsigned u; } x; x.f = f;
  unsigned r = x.u + 0x7fffu + ((x.u >> 16) & 1u);
  return (u16)(r >> 16);
}
__device__ inline float bf2f(u16 u){
  union { unsigned u; float f; } x; x.u = ((unsigned)u) << 16; return x.f;
}
__device__ inline float asf(unsigned u){
  union { unsigned u; float f; } x; x.u = u; return x.f;
}
// HW RTNE pack: low16 = bf16(a), high16 = bf16(b)
__device__ inline unsigned cvtpk(float a, float b){
  unsigned r;
  asm("v_cvt_pk_bf16_f32 %0, %1, %2" : "=v"(r) : "v"(a), "v"(b));
  return r;
}
__device__ inline bf16x8 ldfrag(const u16* a, int outer, int k0, int lm, int lh){
  return *(const bf16x8*)(a + (size_t)(outer + lm)*ST2 + k0 + 8*lh);
}
// Barrier draining only LDS (lgkmcnt), not global traffic.
__device__ inline void lds_barrier(){
  __builtin_amdgcn_sched_barrier(0);
  asm volatile("s_waitcnt lgkmcnt(0)" ::: "memory");
  __builtin_amdgcn_s_barrier();
  __builtin_amdgcn_sched_barrier(0);
}

// ---------------------------------------------------------------------------
// Merged weight transpose + hi/lo split (unchanged from R12)
// ---------------------------------------------------------------------------
__global__ void __launch_bounds__(256)
wt_split_all(const float* __restrict__ Wq, const float* __restrict__ Wk,
             const float* __restrict__ Wv, const float* __restrict__ Wo,
             u16* __restrict__ wth, u16* __restrict__ wtl,
             u16* __restrict__ woth, u16* __restrict__ wotl)
{
  __shared__ float ts[64][68];
  const int tid = threadIdx.x;
  const int n0 = blockIdx.x*64, k0 = blockIdx.y*64;
  const int tx = tid & 15, ty = tid >> 4;

  const float* src; int N, ncol, dstcol; u16 *dh, *dl;
  if (n0 < 1024)      { src = Wq; N = 1024; ncol = n0;        dstcol = n0;        dh = wth;  dl = wtl;  }
  else if (n0 < 1536) { src = Wk; N = 512;  ncol = n0 - 1024; dstcol = n0;        dh = wth;  dl = wtl;  }
  else if (n0 < 2048) { src = Wv; N = 512;  ncol = n0 - 1536; dstcol = n0;        dh = wth;  dl = wtl;  }
  else                { src = Wo; N = 1024; ncol = n0 - 2048; dstcol = n0 - 2048; dh = woth; dl = wotl; }

#pragma unroll
  for (int i = 0; i < 4; ++i) {
    int k = ty + i*16;
    float4 v = *(const float4*)(src + (size_t)(k0+k)*N + ncol + tx*4);
    ts[k][tx*4+0]=v.x; ts[k][tx*4+1]=v.y; ts[k][tx*4+2]=v.z; ts[k][tx*4+3]=v.w;
  }
  __syncthreads();
#pragma unroll
  for (int i = 0; i < 4; ++i) {
    int n = ty + i*16;
    ushort4 uh, ul;
    float f0 = ts[tx*4+0][n], f1 = ts[tx*4+1][n];
    float f2 = ts[tx*4+2][n], f3 = ts[tx*4+3][n];
    uh.x = f2bf(f0); ul.x = f2bf(f0 - bf2f(uh.x));
    uh.y = f2bf(f1); ul.y = f2bf(f1 - bf2f(uh.y));
    uh.z = f2bf(f2); ul.z = f2bf(f2 - bf2f(uh.z));
    uh.w = f2bf(f3); ul.w = f2bf(f3 - bf2f(uh.w));
    *(ushort4*)(dh + (size_t)(dstcol+n)*GK + k0 + tx*4) = uh;
    *(ushort4*)(dl + (size_t)(dstcol+n)*GK + k0 + tx*4) = ul;
  }
}

// ---------------------------------------------------------------------------
// QKV GEMM, R14 = R12 version: split-x (hi/lo reg-staged) x split-W, 3 MFMA.
// x precision is recurrence-critical (R13 ablation: dropping x_lo = +0.03).
// ---------------------------------------------------------------------------
__global__ void __launch_bounds__(256)
gemm_qkv(const float* __restrict__ x,
         const u16* __restrict__ Bth, const u16* __restrict__ Btl,
         u16* __restrict__ qb, u16* __restrict__ kb, float* __restrict__ vb,
         const float* __restrict__ cosb, const float* __restrict__ sinb)
{
  __shared__ u16 AsH[128*64];
  __shared__ u16 AsL[128*64];
  __shared__ u16 BsH[128*64];
  __shared__ u16 BsL[128*64];

  const int tid = threadIdx.x;
  const int w = tid >> 6, l = tid & 63, lm = l & 15, lh = l >> 4;
  const int bm = blockIdx.y << 7, bn = blockIdx.x << 7;
  const int wr = w >> 1, wc = w & 1;

  f32x4 acc[4][4];
#pragma unroll
  for (int i = 0; i < 4; ++i)
#pragma unroll
    for (int j = 0; j < 4; ++j) { f32x4 z = {0.f,0.f,0.f,0.f}; acc[i][j] = z; }

  const int lr8 = l >> 3, sp = l & 7;
  const int ar = tid >> 3, as_ = tid & 7;

  for (int kt = 0; kt < GK; kt += 64) {
    __syncthreads();
#pragma unroll
    for (int c = 0; c < 4; ++c) {
      const int r = (w*4 + c)*8 + lr8;
      const int s = sp ^ (r & 7);
      const u16* gh = Bth + (size_t)(bn + r)*GK + kt + s*8;
      const u16* gl = Btl + (size_t)(bn + r)*GK + kt + s*8;
      __builtin_amdgcn_global_load_lds(
        (const __attribute__((address_space(1))) void*)gh,
        (__attribute__((address_space(3))) void*)(BsH + (w*4 + c)*512), 16, 0, 0);
      __builtin_amdgcn_global_load_lds(
        (const __attribute__((address_space(1))) void*)gl,
        (__attribute__((address_space(3))) void*)(BsL + (w*4 + c)*512), 16, 0, 0);
    }
#pragma unroll
    for (int p = 0; p < 4; ++p) {
      const int r = p*32 + ar;
      const float* gx = x + (size_t)(bm + r)*NEMB + kt + as_*8;
      float4 f0 = *(const float4*)gx;
      float4 f1 = *(const float4*)(gx + 4);
      float fv[8] = {f0.x,f0.y,f0.z,f0.w,f1.x,f1.y,f1.z,f1.w};
      uint4 hq, lq;
      hq.x = cvtpk(fv[0], fv[1]); hq.y = cvtpk(fv[2], fv[3]);
      hq.z = cvtpk(fv[4], fv[5]); hq.w = cvtpk(fv[6], fv[7]);
      float l0 = fv[0] - asf(hq.x << 16), l1 = fv[1] - asf(hq.x & 0xffff0000u);
      float l2 = fv[2] - asf(hq.y << 16), l3 = fv[3] - asf(hq.y & 0xffff0000u);
      float l4 = fv[4] - asf(hq.z << 16), l5 = fv[5] - asf(hq.z & 0xffff0000u);
      float l6 = fv[6] - asf(hq.w << 16), l7 = fv[7] - asf(hq.w & 0xffff0000u);
      lq.x = cvtpk(l0, l1); lq.y = cvtpk(l2, l3);
      lq.z = cvtpk(l4, l5); lq.w = cvtpk(l6, l7);
      const int off = r*64 + (as_ ^ (r & 7))*8;
      *(uint4*)&AsH[off] = hq;
      *(uint4*)&AsL[off] = lq;
    }
    __syncthreads();
#pragma unroll
    for (int kk = 0; kk < 2; ++kk) {
      bf16x8 ah[4], al[4], bh[4], bl[4];
#pragma unroll
      for (int mi = 0; mi < 4; ++mi) {
        int r = wr*64 + mi*16 + lm;
        int s = (kk*4 + lh) ^ (r & 7);
        ah[mi] = *(const bf16x8*)(AsH + r*64 + s*8);
        al[mi] = *(const bf16x8*)(AsL + r*64 + s*8);
      }
#pragma unroll
      for (int nj = 0; nj < 4; ++nj) {
        int r = wc*64 + nj*16 + lm;
        int s = (kk*4 + lh) ^ (r & 7);
        bh[nj] = *(const bf16x8*)(BsH + r*64 + s*8);
        bl[nj] = *(const bf16x8*)(BsL + r*64 + s*8);
      }
#pragma unroll
      for (int mi = 0; mi < 4; ++mi)
#pragma unroll
        for (int nj = 0; nj < 4; ++nj) {
          acc[mi][nj] = __builtin_amdgcn_mfma_f32_16x16x32_bf16(ah[mi], bh[nj], acc[mi][nj], 0,0,0);
          acc[mi][nj] = __builtin_amdgcn_mfma_f32_16x16x32_bf16(al[mi], bh[nj], acc[mi][nj], 0,0,0);
          acc[mi][nj] = __builtin_amdgcn_mfma_f32_16x16x32_bf16(ah[mi], bl[nj], acc[mi][nj], 0,0,0);
        }
    }
  }

  const int colbase = bn + wc*64;
  if (colbase < VOFF) {
    u16* C; int ldcc, cb2;
    if (colbase < KOFF) { C = qb; ldcc = NH*DD;  cb2 = colbase; }
    else                { C = kb; ldcc = NKV*DD; cb2 = colbase - KOFF; }
#pragma unroll
    for (int mi = 0; mi < 4; ++mi) {
#pragma unroll
      for (int r = 0; r < 4; ++r) {
        const int rl = wr*64 + mi*16 + 4*lh + r;
        const int t = (bm + rl) & (TT - 1);
        const float c0 = cosb[t*32 + lm],      s0 = sinb[t*32 + lm];
        const float c1 = cosb[t*32 + 16 + lm], s1 = sinb[t*32 + 16 + lm];
        float o0 = acc[mi][0][r]*c0 - acc[mi][2][r]*s0;
        float o1 = acc[mi][1][r]*c1 - acc[mi][3][r]*s1;
        float o2 = acc[mi][2][r]*c0 + acc[mi][0][r]*s0;
        float o3 = acc[mi][3][r]*c1 + acc[mi][1][r]*s1;
        float ss = o0*o0 + o1*o1 + o2*o2 + o3*o3;
        ss += __shfl_xor(ss, 1); ss += __shfl_xor(ss, 2);
        ss += __shfl_xor(ss, 4); ss += __shfl_xor(ss, 8);
        const float rr = rsqrtf(ss*(1.f/64.f) + 1e-6f);
        u16* dst = C + (size_t)(bm + rl)*ldcc + cb2 + lm;
        dst[0]  = f2bf(o0*rr);
        dst[16] = f2bf(o1*rr);
        dst[32] = f2bf(o2*rr);
        dst[48] = f2bf(o3*rr);
      }
    }
  } else {
    const int cb2 = colbase - VOFF;
#pragma unroll
    for (int mi = 0; mi < 4; ++mi)
#pragma unroll
      for (int nj = 0; nj < 4; ++nj)
#pragma unroll
        for (int r = 0; r < 4; ++r) {
          const int rl = wr*64 + mi*16 + 4*lh + r;
          vb[(size_t)(bm + rl)*(NKV*DD) + cb2 + nj*16 + lm] = acc[mi][nj][r];
        }
  }
}

// ---------------------------------------------------------------------------
// Out GEMM, R14 = R13 version: A = y_hi only; B = split Wo. 2 MFMA per step.
// (y_lo drop costs ~0.004 abs at the final linear pass only.)
// ---------------------------------------------------------------------------
__global__ void __launch_bounds__(256)
gemm_out(const u16* __restrict__ Ah,
         const u16* __restrict__ Bth, const u16* __restrict__ Btl,
         float* __restrict__ C)
{
  __shared__ u16 As[128*64];
  __shared__ u16 BsH[128*64];
  __shared__ u16 BsL[128*64];
  const int tid = threadIdx.x;
  const int w = tid >> 6, l = tid & 63, lm = l & 15, lh = l >> 4;
  const int bm = blockIdx.y << 7, bn = blockIdx.x << 7;
  const int wr = w >> 1, wc = w & 1;

  f32x4 acc[4][4];
#pragma unroll
  for (int i = 0; i < 4; ++i)
#pragma unroll
    for (int j = 0; j < 4; ++j) { f32x4 z = {0.f,0.f,0.f,0.f}; acc[i][j] = z; }

  const int lr8 = l >> 3, sp = l & 7;
  for (int kt = 0; kt < GK; kt += 64) {
    __syncthreads();
#pragma unroll
    for (int c = 0; c < 4; ++c) {
      const int r = (w*4 + c)*8 + lr8;
      const int s = sp ^ (r & 7);
      const u16* gah = Ah  + (size_t)(bm + r)*(NH*DD) + kt + s*8;
      const u16* gbh = Bth + (size_t)(bn + r)*GK      + kt + s*8;
      const u16* gbl = Btl + (size_t)(bn + r)*GK      + kt + s*8;
      __builtin_amdgcn_global_load_lds(
        (const __attribute__((address_space(1))) void*)gah,
        (__attribute__((address_space(3))) void*)(As + (w*4 + c)*512), 16, 0, 0);
      __builtin_amdgcn_global_load_lds(
        (const __attribute__((address_space(1))) void*)gbh,
        (__attribute__((address_space(3))) void*)(BsH + (w*4 + c)*512), 16, 0, 0);
      __builtin_amdgcn_global_load_lds(
        (const __attribute__((address_space(1))) void*)gbl,
        (__attribute__((address_space(3))) void*)(BsL + (w*4 + c)*512), 16, 0, 0);
    }
    __syncthreads();
#pragma unroll
    for (int kk = 0; kk < 2; ++kk) {
      bf16x8 av[4], bh[4], bl[4];
#pragma unroll
      for (int mi = 0; mi < 4; ++mi) {
        int r = wr*64 + mi*16 + lm;
        int s = (kk*4 + lh) ^ (r & 7);
        av[mi] = *(const bf16x8*)(As + r*64 + s*8);
      }
#pragma unroll
      for (int nj = 0; nj < 4; ++nj) {
        int r = wc*64 + nj*16 + lm;
        int s = (kk*4 + lh) ^ (r & 7);
        bh[nj] = *(const bf16x8*)(BsH + r*64 + s*8);
        bl[nj] = *(const bf16x8*)(BsL + r*64 + s*8);
      }
#pragma unroll
      for (int mi = 0; mi < 4; ++mi)
#pragma unroll
        for (int nj = 0; nj < 4; ++nj) {
          acc[mi][nj] = __builtin_amdgcn_mfma_f32_16x16x32_bf16(av[mi], bh[nj], acc[mi][nj], 0,0,0);
          acc[mi][nj] = __builtin_amdgcn_mfma_f32_16x16x32_bf16(av[mi], bl[nj], acc[mi][nj], 0,0,0);
        }
    }
  }
#pragma unroll
  for (int mi = 0; mi < 4; ++mi)
#pragma unroll
    for (int nj = 0; nj < 4; ++nj)
#pragma unroll
      for (int r = 0; r < 4; ++r) {
        const int rl = wr*64 + mi*16 + 4*lh + r;
        C[(size_t)(bm + rl)*NEMB + bn + wc*64 + nj*16 + lm] = acc[mi][nj][r];
      }
}

// ---------------------------------------------------------------------------
// eta = softplus(x @ lr_w + lr_b)  (unchanged)
// ---------------------------------------------------------------------------
__global__ void __launch_bounds__(256)
eta_kernel(const float* __restrict__ x, const float* __restrict__ lr_w,
           const float* __restrict__ lr_b, float* __restrict__ etab)
{
  __shared__ float lw[NKV*NEMB];
  const int tid = threadIdx.x;
  for (int idx = tid; idx < NEMB*NKV; idx += 256) {
    int i = idx >> 3, k2 = idx & 7;
    lw[k2*NEMB + i] = lr_w[idx];
  }
  __syncthreads();
  const int w = tid >> 6, lane = tid & 63;
  const size_t tok = (size_t)blockIdx.x*4 + w;
  const float* xr = x + tok*NEMB;
  float acc[8] = {0.f,0.f,0.f,0.f,0.f,0.f,0.f,0.f};
  for (int j = 0; j < 16; ++j) {
    float xv = xr[lane + 64*j];
#pragma unroll
    for (int k2 = 0; k2 < 8; ++k2)
      acc[k2] += xv * lw[k2*NEMB + lane + 64*j];
  }
#pragma unroll
  for (int k2 = 0; k2 < 8; ++k2)
#pragma unroll
    for (int off = 32; off; off >>= 1) acc[k2] += __shfl_xor(acc[k2], off);
  if (lane == 0) {
#pragma unroll
    for (int k2 = 0; k2 < 8; ++k2) {
      float z = acc[k2] + lr_b[k2];
      etab[tok*NKV + k2] = (z > 20.f) ? z : log1pf(expf(z));
    }
  }
}

// ---------------------------------------------------------------------------
// MFMA TTT scan (R13 version: y single-plane bf16, no setprio)
// ---------------------------------------------------------------------------
__global__ void __launch_bounds__(512, 2)
scan_mfma(const u16* __restrict__ qsrc, u16* __restrict__ yhi,
          const u16* __restrict__ kbuf,
          const float* __restrict__ vbuf, const float* __restrict__ etabuf,
          const float* __restrict__ onw, const float* __restrict__ wis_p)
{
  extern __shared__ char smraw[];
  u16* KbT = (u16*)smraw;             // [64][ST2] K^T[d][c]
  u16* Qb0 = KbT + 64*ST2;            // [64][ST2] Q_h0[c][d]
  u16* Qb1 = Qb0 + 64*ST2;            // [64][ST2] Q_h1[c][d]
  u16* Ab0 = Qb1 + 64*ST2;            // [64][ST2] A_h0[ci][cj]
  u16* Ab1 = Ab0 + 64*ST2;            // [64][ST2] A_h1[ci][cj]
  u16* EsT = Ab1 + 64*ST2;            // [64][ST2] negEs^T[e][c]
  u16* WbT = EsT + 64*ST2;            // [64][ST2] W^T[e][d] bf16
  float* colp = (float*)(WbT + 64*ST2); // [64][4]
  float* onws = colp + 64*4;          // [64]

  const int tid = threadIdx.x;
  const int b = blockIdx.x >> 3, kh = blockIdx.x & 7;
  const int w = tid >> 6, l = tid & 63, lm = l & 15, lh = l >> 4;
  const bool gA = (w < 4);
  const int m0 = (w & 3) * 16;
  const int cb = m0 + lh*4;
  const float wis = *wis_p;

  float Wreg[4][4];   // A-group only
  if (gA) {
#pragma unroll
    for (int n = 0; n < 4; ++n) {
      const int e = n*16 + lm;
#pragma unroll
      for (int r = 0; r < 4; ++r)
        Wreg[n][r] = ((cb + r) == e) ? wis : 0.f;
      uint2 u;
      u.x = cvtpk(Wreg[n][0], Wreg[n][1]);
      u.y = cvtpk(Wreg[n][2], Wreg[n][3]);
      *(uint2*)&WbT[e*ST2 + cb] = u;
    }
  }
  if (tid < 64) onws[tid] = onw[tid];

  const int st = tid & 255;           // staging index within group B
  const int stc4 = (st >> 4)*4;
  const int std4 = (st & 15)*4;

  ushort4 kpre[4], qpre0[4], qpre1[4];   // group B staging regs
  bf16x8 akp0, akp1, ak0, ak1;           // all waves
  float vpre[4][4], vcur[4][4];          // group A
  float epre[4], ecur[4];                // group A
  float val[4][4];                       // deferred y (both groups)

#define LOAD_PF(CH)                                                            \
  { const size_t rb = (size_t)b*TT + (size_t)(CH)*64;                          \
    if (!gA) {                                                                 \
      _Pragma("unroll")                                                        \
      for (int i = 0; i < 4; ++i) {                                            \
        kpre[i]  = *(const ushort4*)(kbuf + (rb+stc4+i)*(NKV*DD) + kh*DD + std4);\
        qpre0[i] = *(const ushort4*)(qsrc + (rb+stc4+i)*(NH*DD) + (kh*2)*DD + std4);\
        qpre1[i] = *(const ushort4*)(qsrc + (rb+stc4+i)*(NH*DD) + (kh*2+1)*DD + std4);\
      }                                                                        \
    }                                                                          \
    akp0 = *(const bf16x8*)(kbuf + (rb+m0+lm)*(NKV*DD) + kh*DD + 8*lh);        \
    akp1 = *(const bf16x8*)(kbuf + (rb+m0+lm)*(NKV*DD) + kh*DD + 32 + 8*lh);   \
    if (gA) {                                                                  \
      _Pragma("unroll")                                                        \
      for (int n = 0; n < 4; ++n)                                              \
        _Pragma("unroll")                                                      \
        for (int r = 0; r < 4; ++r)                                            \
          vpre[n][r] = vbuf[(rb+cb+r)*(NKV*DD) + kh*DD + n*16 + lm];           \
      _Pragma("unroll")                                                        \
      for (int r = 0; r < 4; ++r) epre[r] = etabuf[(rb+cb+r)*NKV + kh];        \
    } }

#define PROMOTE()                                                              \
  { ak0 = akp0; ak1 = akp1;                                                    \
    if (gA) {                                                                  \
      _Pragma("unroll")                                                        \
      for (int n = 0; n < 4; ++n)                                              \
        _Pragma("unroll")                                                      \
        for (int r = 0; r < 4; ++r) vcur[n][r] = vpre[n][r];                   \
      _Pragma("unroll")                                                        \
      for (int r = 0; r < 4; ++r) ecur[r] = epre[r];                           \
    } else {                                                                   \
      ushort4 u;                                                               \
      u.x=kpre[0].x; u.y=kpre[1].x; u.z=kpre[2].x; u.w=kpre[3].x;              \
      *(ushort4*)&KbT[(std4+0)*ST2 + stc4] = u;                                \
      u.x=kpre[0].y; u.y=kpre[1].y; u.z=kpre[2].y; u.w=kpre[3].y;              \
      *(ushort4*)&KbT[(std4+1)*ST2 + stc4] = u;                                \
      u.x=kpre[0].z; u.y=kpre[1].z; u.z=kpre[2].z; u.w=kpre[3].z;              \
      *(ushort4*)&KbT[(std4+2)*ST2 + stc4] = u;                                \
      u.x=kpre[0].w; u.y=kpre[1].w; u.z=kpre[2].w; u.w=kpre[3].w;              \
      *(ushort4*)&KbT[(std4+3)*ST2 + stc4] = u;                                \
      _Pragma("unroll")                                                        \
      for (int i = 0; i < 4; ++i) {                                            \
        *(ushort4*)&Qb0[(stc4+i)*ST2 + std4] = qpre0[i];                       \
        *(ushort4*)&Qb1[(stc4+i)*ST2 + std4] = qpre1[i];                       \
      }                                                                        \
    } }

#define STORE_Y(RB)                                                            \
  { const int ho = (kh*2 + (gA ? 0 : 1))*DD;                                   \
    _Pragma("unroll")                                                          \
    for (int n = 0; n < 4; ++n) {                                              \
      const int e = n*16 + lm;                                                 \
      unsigned h01 = cvtpk(val[n][0], val[n][1]);                              \
      unsigned h23 = cvtpk(val[n][2], val[n][3]);                              \
      const size_t i0 = ((RB) + cb)*(size_t)(NH*DD) + ho + e;                  \
      yhi[i0]           = (u16)h01;                                            \
      yhi[i0 + NH*DD]   = (u16)(h01 >> 16);                                    \
      yhi[i0 + 2*NH*DD] = (u16)h23;                                            \
      yhi[i0 + 3*NH*DD] = (u16)(h23 >> 16);                                    \
    } }

  LOAD_PF(0);
  PROMOTE();
  lds_barrier();

  f32x4 oc[4];
  bf16x8 wfr[8];

  for (int ch = 0; ch < NCH; ++ch) {
    const size_t rowbase = (size_t)b*TT + (size_t)ch*64;

    if (ch < NCH-1) LOAD_PF(ch+1);
    if (ch > 0) STORE_Y(rowbase - 64);   // prev chunk's y; never blocks

    // ---------------- phase1 ----------------
    if (gA) {
      // E = K·W -> Es; then Q0·W partial for out_h0
      f32x4 eac[4];
#pragma unroll
      for (int n = 0; n < 4; ++n) { f32x4 z = {0.f,0.f,0.f,0.f}; eac[n] = z; }
#pragma unroll
      for (int n = 0; n < 4; ++n) {
        wfr[2*n]   = ldfrag(WbT, n*16,  0, lm, lh);
        wfr[2*n+1] = ldfrag(WbT, n*16, 32, lm, lh);
        eac[n] = __builtin_amdgcn_mfma_f32_16x16x32_bf16(ak0, wfr[2*n],   eac[n], 0,0,0);
        eac[n] = __builtin_amdgcn_mfma_f32_16x16x32_bf16(ak1, wfr[2*n+1], eac[n], 0,0,0);
      }
#pragma unroll
      for (int n = 0; n < 4; ++n) {
        const int e = n*16 + lm;
        uint2 u;
        u.x = cvtpk(ecur[0]*(vcur[n][0] - eac[n][0]),
                    ecur[1]*(vcur[n][1] - eac[n][1]));
        u.y = cvtpk(ecur[2]*(vcur[n][2] - eac[n][2]),
                    ecur[3]*(vcur[n][3] - eac[n][3]));
        *(uint2*)&EsT[e*ST2 + cb] = u;
      }
      bf16x8 aQ0 = ldfrag(Qb0, m0, 0, lm, lh), aQ1 = ldfrag(Qb0, m0, 32, lm, lh);
#pragma unroll
      for (int n = 0; n < 4; ++n) {
        f32x4 z = {0.f,0.f,0.f,0.f};
        z = __builtin_amdgcn_mfma_f32_16x16x32_bf16(aQ0, wfr[2*n],   z, 0,0,0);
        z = __builtin_amdgcn_mfma_f32_16x16x32_bf16(aQ1, wfr[2*n+1], z, 0,0,0);
        oc[n] = z;
      }
    } else {
      // AT = K·Q^T both heads; mask tril -> Ab0/Ab1; prefetch wfr for phase2
      f32x4 a0c[4], a1c[4];
#pragma unroll
      for (int n = 0; n < 4; ++n) { f32x4 z = {0.f,0.f,0.f,0.f}; a0c[n] = z; a1c[n] = z; }
#pragma unroll
      for (int n = 0; n < 4; ++n) {
        a0c[n] = __builtin_amdgcn_mfma_f32_16x16x32_bf16(ak0, ldfrag(Qb0, n*16,  0, lm, lh), a0c[n], 0,0,0);
        a0c[n] = __builtin_amdgcn_mfma_f32_16x16x32_bf16(ak1, ldfrag(Qb0, n*16, 32, lm, lh), a0c[n], 0,0,0);
        a1c[n] = __builtin_amdgcn_mfma_f32_16x16x32_bf16(ak0, ldfrag(Qb1, n*16,  0, lm, lh), a1c[n], 0,0,0);
        a1c[n] = __builtin_amdgcn_mfma_f32_16x16x32_bf16(ak1, ldfrag(Qb1, n*16, 32, lm, lh), a1c[n], 0,0,0);
      }
#pragma unroll
      for (int n = 0; n < 4; ++n) {
        const int ci = n*16 + lm;
        uint2 u0, u1;
        u0.x = cvtpk((cb+0 <= ci) ? a0c[n][0] : 0.f, (cb+1 <= ci) ? a0c[n][1] : 0.f);
        u0.y = cvtpk((cb+2 <= ci) ? a0c[n][2] : 0.f, (cb+3 <= ci) ? a0c[n][3] : 0.f);
        u1.x = cvtpk((cb+0 <= ci) ? a1c[n][0] : 0.f, (cb+1 <= ci) ? a1c[n][1] : 0.f);
        u1.y = cvtpk((cb+2 <= ci) ? a1c[n][2] : 0.f, (cb+3 <= ci) ? a1c[n][3] : 0.f);
        *(uint2*)&Ab0[ci*ST2 + cb] = u0;
        *(uint2*)&Ab1[ci*ST2 + cb] = u1;
      }
#pragma unroll
      for (int n = 0; n < 4; ++n) {
        wfr[2*n]   = ldfrag(WbT, n*16,  0, lm, lh);
        wfr[2*n+1] = ldfrag(WbT, n*16, 32, lm, lh);
      }
    }
    lds_barrier();

    // ---------------- phase2 ----------------
    {
      bf16x8 esf[8];
#pragma unroll
      for (int n = 0; n < 4; ++n) {
        esf[2*n]   = ldfrag(EsT, n*16,  0, lm, lh);
        esf[2*n+1] = ldfrag(EsT, n*16, 32, lm, lh);
      }
      if (gA) {
        bf16x8 aA0 = ldfrag(Ab0, m0, 0, lm, lh), aA1 = ldfrag(Ab0, m0, 32, lm, lh);
#pragma unroll
        for (int n = 0; n < 4; ++n) {
          oc[n] = __builtin_amdgcn_mfma_f32_16x16x32_bf16(aA0, esf[2*n],   oc[n], 0,0,0);
          oc[n] = __builtin_amdgcn_mfma_f32_16x16x32_bf16(aA1, esf[2*n+1], oc[n], 0,0,0);
        }
        float rr[4];
#pragma unroll
        for (int r = 0; r < 4; ++r) {
          float s = oc[0][r]*oc[0][r] + oc[1][r]*oc[1][r]
                  + oc[2][r]*oc[2][r] + oc[3][r]*oc[3][r];
          s += __shfl_xor(s, 1); s += __shfl_xor(s, 2);
          s += __shfl_xor(s, 4); s += __shfl_xor(s, 8);
          rr[r] = rsqrtf(s*(1.f/64.f) + 1e-6f);
        }
#pragma unroll
        for (int n = 0; n < 4; ++n) {
          const float ow = onws[n*16 + lm];
#pragma unroll
          for (int r = 0; r < 4; ++r) val[n][r] = oc[n][r]*rr[r]*ow;
        }
        // U' = K^T·negEs; W += U'/64; colnorm partials
        bf16x8 aT0 = ldfrag(KbT, m0, 0, lm, lh), aT1 = ldfrag(KbT, m0, 32, lm, lh);
#pragma unroll
        for (int n = 0; n < 4; ++n) {
          f32x4 z = {0.f,0.f,0.f,0.f};
          z = __builtin_amdgcn_mfma_f32_16x16x32_bf16(aT0, esf[2*n],   z, 0,0,0);
          z = __builtin_amdgcn_mfma_f32_16x16x32_bf16(aT1, esf[2*n+1], z, 0,0,0);
          float p = 0.f;
#pragma unroll
          for (int r = 0; r < 4; ++r) {
            Wreg[n][r] += z[r]*(1.f/64.f);
            p += Wreg[n][r]*Wreg[n][r];
          }
          p += __shfl_xor(p, 16);
          p += __shfl_xor(p, 32);
          if (lh == 0) colp[(n*16 + lm)*4 + (w & 3)] = p;
        }
      } else {
        bf16x8 aQ0 = ldfrag(Qb1, m0, 0, lm, lh), aQ1 = ldfrag(Qb1, m0, 32, lm, lh);
        bf16x8 aA0 = ldfrag(Ab1, m0, 0, lm, lh), aA1 = ldfrag(Ab1, m0, 32, lm, lh);
#pragma unroll
        for (int n = 0; n < 4; ++n) {
          f32x4 z = {0.f,0.f,0.f,0.f};
          z = __builtin_amdgcn_mfma_f32_16x16x32_bf16(aQ0, wfr[2*n],   z, 0,0,0);
          z = __builtin_amdgcn_mfma_f32_16x16x32_bf16(aQ1, wfr[2*n+1], z, 0,0,0);
          z = __builtin_amdgcn_mfma_f32_16x16x32_bf16(aA0, esf[2*n],   z, 0,0,0);
          z = __builtin_amdgcn_mfma_f32_16x16x32_bf16(aA1, esf[2*n+1], z, 0,0,0);
          oc[n] = z;
        }
        float rr[4];
#pragma unroll
        for (int r = 0; r < 4; ++r) {
          float s = oc[0][r]*oc[0][r] + oc[1][r]*oc[1][r]
                  + oc[2][r]*oc[2][r] + oc[3][r]*oc[3][r];
          s += __shfl_xor(s, 1); s += __shfl_xor(s, 2);
          s += __shfl_xor(s, 4); s += __shfl_xor(s, 8);
          rr[r] = rsqrtf(s*(1.f/64.f) + 1e-6f);
        }
#pragma unroll
        for (int n = 0; n < 4; ++n) {
          const float ow = onws[n*16 + lm];
#pragma unroll
          for (int r = 0; r < 4; ++r) val[n][r] = oc[n][r]*rr[r]*ow;
        }
      }
    }
    lds_barrier();

    // ---------------- finalize ----------------
    if (gA) {
#pragma unroll
      for (int n = 0; n < 4; ++n) {
        const int e = n*16 + lm;
        float s = colp[e*4+0] + colp[e*4+1] + colp[e*4+2] + colp[e*4+3];
        float rv = 1.f / fmaxf(sqrtf(s), 1e-12f);
#pragma unroll
        for (int r = 0; r < 4; ++r) Wreg[n][r] *= rv;
        uint2 u;
        u.x = cvtpk(Wreg[n][0], Wreg[n][1]);
        u.y = cvtpk(Wreg[n][2], Wreg[n][3]);
        *(uint2*)&WbT[e*ST2 + cb] = u;
      }
    }
    if (ch < NCH-1) PROMOTE();
    lds_barrier();
  }
  // last chunk's y
  STORE_Y((size_t)b*TT + (size_t)(NCH-1)*64);
#undef LOAD_PF
#undef PROMOTE
#undef STORE_Y
}

// ---------------------------------------------------------------------------
extern "C" void kernel_launch(void* const* d_in, const int* in_sizes, int n_in,
                              void* d_out, int out_size, void* d_ws, size_t ws_size,
                              hipStream_t stream)
{
  (void)in_sizes; (void)n_in; (void)out_size;
  const float* x    = (const float*)d_in[0];
  const float* cosb = (const float*)d_in[1];
  const float* sinb = (const float*)d_in[2];
  const float* Wq   = (const float*)d_in[3];
  const float* Wk   = (const float*)d_in[4];
  const float* Wv   = (const float*)d_in[5];
  const float* Wo   = (const float*)d_in[6];
  const float* lrw  = (const float*)d_in[7];
  const float* lrb  = (const float*)d_in[8];
  const float* onw  = (const float*)d_in[9];
  const float* wis  = (const float*)d_in[10];
  float* out = (float*)d_out;

  const size_t qN   = (size_t)BTOT*NH*DD;      // u16 (q, later y_hi)
  const size_t kN   = (size_t)BTOT*NKV*DD;     // u16
  const size_t wtN  = (size_t)2048*GK;         // u16 per plane
  const size_t wotN = (size_t)1024*GK;         // u16 per plane
  const size_t vN   = (size_t)BTOT*NKV*DD;     // f32
  const size_t etaN = (size_t)BTOT*NKV;        // f32
  const size_t need = (qN + kN + wtN*2 + wotN*2)*2 + (vN + etaN)*4;
  if (ws_size < need) return;

  u16* qbuf  = (u16*)d_ws;          // q, then y_hi
  u16* kbuf  = qbuf + qN;
  u16* wth   = kbuf + kN;
  u16* wtl   = wth + wtN;
  u16* woth  = wtl + wtN;
  u16* wotl  = woth + wotN;
  float* vbuf = (float*)(wotl + wotN);
  float* etab = vbuf + vN;

  wt_split_all<<<dim3(48,16), 256, 0, stream>>>(Wq, Wk, Wv, Wo,
                                                wth, wtl, woth, wotl);

  gemm_qkv<<<dim3(16,128), 256, 0, stream>>>(x, wth, wtl, qbuf, kbuf, vbuf, cosb, sinb);
  eta_kernel<<<BTOT/4, 256, 0, stream>>>(x, lrw, lrb, etab);

  const size_t SMEM = (size_t)(7*64*ST2)*2 + (size_t)(64*4 + 64)*4;  // 72960 B
  hipFuncSetAttribute(reinterpret_cast<const void*>(scan_mfma),
                      hipFuncAttributeMaxDynamicSharedMemorySize, (int)SMEM);
  scan_mfma<<<32, 512, SMEM, stream>>>(qbuf, qbuf, kbuf, vbuf, etab, onw, wis);

  gemm_out<<<dim3(8,128), 256, 0, stream>>>(qbuf, woth, wotl, out);
}